// Round 2
// baseline (735.496 us; speedup 1.0000x reference)
//
#include <hip/hip_runtime.h>
#include <cstdint>
#include <cstddef>

// QuantLlamaAttention: int8 fake-quant Llama attention block, MI355X (gfx950).
// All matmuls carry quantized INTEGER values in _Float16 (exact for |v|<=2048)
// through mfma_f32_16x16x32_f16, fp32 accumulate, scales applied in epilogue.
// softmax prob amax is exactly 1.0 (causal row 0) -> static prob scale 1/127,
// enabling a two-pass flash attention with exact quantization (no S matrix).
//
// R1: same-address atomicMax serialization -> block partials / 1 atomic per block.
// R2: k_attn 368us: __expf, rcp prob scale, diag-only masking, q-tile pairing,
//     GEMM k-loop -> m97-style global_load_lds width=16.
// R3: k_attn 147us @ Mfma 14 / Occ 20 (latency-bound, grid=2 blocks/CU):
//     - grid (32,32) one qb/block + CU-balanced qb mapping (4 blocks/CU sum to
//       66 k-tile units under stride-256 co-residency model)
//     - LDS 45->40KB exact (4 blocks/CU): pads dropped, 16B-chunk XOR swizzle
//       (chunk ^= row&7) on sK/sV/sP -> balanced 8-way b128, conflict-free
//     - pass1: K double-buffered across the two 16KB regions, 1 barrier/ktile,
//       prefetch under MFMA; pass2: wave-private sP barrier removed (3->2),
//       next-tile prefetch issued before PV (T14); setprio around MFMA.
// R4: resubmit of R3 (container acquire flake, no counters); OOB/barrier/swizzle
//     re-audited clean.

#define S_LEN   2048
#define HDIM    4096
#define NHEADS  32
#define NKVH    8
#define HEADD   128
#define QMAXF   127.0f
#define ROPE_BLOCKS 20480

typedef _Float16 half8  __attribute__((ext_vector_type(8)));
typedef float    floatx4 __attribute__((ext_vector_type(4)));

// ---------------- helpers ----------------
__device__ __forceinline__ float wave_max64(float v){
#pragma unroll
  for (int off = 32; off > 0; off >>= 1) v = fmaxf(v, __shfl_xor(v, off));
  return v;
}
__device__ __forceinline__ float grp16_max(float v){
#pragma unroll
  for (int off = 8; off > 0; off >>= 1) v = fmaxf(v, __shfl_xor(v, off));
  return v;
}
__device__ __forceinline__ float grp16_sum(float v){
#pragma unroll
  for (int off = 8; off > 0; off >>= 1) v += __shfl_xor(v, off);
  return v;
}
__device__ __forceinline__ void atomic_max_f(unsigned* p, float v){
  atomicMax(p, __float_as_uint(v));   // v >= 0: uint bits order-preserving
}
__device__ __forceinline__ float q8(float x, float scale){
  return fminf(fmaxf(rintf(x / scale), -128.f), 127.f);  // rintf = half-even, matches jnp.round
}
// async global->LDS, 16B per lane. HW: LDS dest = wave-uniform base + lane*16.
__device__ __forceinline__ void gload_lds16(const _Float16* g, _Float16* l){
  __builtin_amdgcn_global_load_lds((const __attribute__((address_space(1))) void*)g,
                                   (__attribute__((address_space(3))) void*)l, 16, 0, 0);
}

// block-level max of per-wave maxima (256 threads = 4 waves), then ONE atomic
__device__ __forceinline__ void block_atomic_max(float m, unsigned* out){
  m = wave_max64(m);
  __shared__ float red[4];
  int wid = threadIdx.x >> 6;
  if ((threadIdx.x & 63) == 0) red[wid] = m;
  __syncthreads();
  if (threadIdx.x == 0)
    atomic_max_f(out, fmaxf(fmaxf(red[0], red[1]), fmaxf(red[2], red[3])));
}

// ---------------- tiny kernels ----------------
__global__ void k_init(float* scal){ if (threadIdx.x < 16) scal[threadIdx.x] = 0.0f; }

__global__ void k_amax(const float* __restrict__ x, size_t n4, unsigned* __restrict__ out){
  size_t i = (size_t)blockIdx.x * blockDim.x + threadIdx.x;
  size_t stride = (size_t)gridDim.x * blockDim.x;
  float m = 0.f;
  for (; i < n4; i += stride){
    float4 v = ((const float4*)x)[i];
    m = fmaxf(m, fmaxf(fmaxf(fabsf(v.x), fabsf(v.y)), fmaxf(fabsf(v.z), fabsf(v.w))));
  }
  block_atomic_max(m, out);
}

// amax over the V slice (cols [5120,6144)) of Y[2048][6144]
__global__ void k_amax_v(const float* __restrict__ Y, unsigned* __restrict__ out){
  size_t i = (size_t)blockIdx.x * blockDim.x + threadIdx.x;
  size_t stride = (size_t)gridDim.x * blockDim.x;
  float m = 0.f;
  for (size_t e = i; e < (size_t)S_LEN * 1024; e += stride){
    size_t s = e >> 10; int c = (int)(e & 1023);
    m = fmaxf(m, fabsf(Y[s * 6144 + 5120 + c]));
  }
  block_atomic_max(m, out);
}

// per-tensor quantize fp32 -> integer-valued f16
__global__ void k_quant(const float* __restrict__ x, _Float16* __restrict__ q,
                        size_t n4, const float* __restrict__ amax){
  float scale = fmaxf(*amax, 1e-8f) / QMAXF;
  size_t i = (size_t)blockIdx.x * blockDim.x + threadIdx.x;
  size_t stride = (size_t)gridDim.x * blockDim.x;
  for (; i < n4; i += stride){
    float4 v = ((const float4*)x)[i];
    union { _Float16 h[4]; uint2 u; } pk;
    pk.h[0] = (_Float16)q8(v.x, scale);
    pk.h[1] = (_Float16)q8(v.y, scale);
    pk.h[2] = (_Float16)q8(v.z, scale);
    pk.h[3] = (_Float16)q8(v.w, scale);
    ((uint2*)q)[i] = pk.u;
  }
}

// per-row weight quantization: rows 0..6143 -> Wall (wq|wk|wv), 6144..10239 -> Wo
__global__ __launch_bounds__(256) void k_quant_w(
    const float* __restrict__ wq, const float* __restrict__ wk,
    const float* __restrict__ wv, const float* __restrict__ wo,
    _Float16* __restrict__ Wall, _Float16* __restrict__ Wo,
    float* __restrict__ wsc)
{
  int row = blockIdx.x;
  const float* src; _Float16* dst;
  if (row < 4096)      { src = wq + (size_t)row * HDIM;          dst = Wall + (size_t)row * HDIM; }
  else if (row < 5120) { src = wk + (size_t)(row - 4096) * HDIM; dst = Wall + (size_t)row * HDIM; }
  else if (row < 6144) { src = wv + (size_t)(row - 5120) * HDIM; dst = Wall + (size_t)row * HDIM; }
  else                 { src = wo + (size_t)(row - 6144) * HDIM; dst = Wo + (size_t)(row - 6144) * HDIM; }
  float4 v[4]; float m = 0.f;
#pragma unroll
  for (int i = 0; i < 4; i++){
    v[i] = ((const float4*)src)[threadIdx.x + i * 256];
    m = fmaxf(m, fmaxf(fmaxf(fabsf(v[i].x), fabsf(v[i].y)), fmaxf(fabsf(v[i].z), fabsf(v[i].w))));
  }
  m = wave_max64(m);
  __shared__ float red[4];
  int wid = threadIdx.x >> 6;
  if ((threadIdx.x & 63) == 0) red[wid] = m;
  __syncthreads();
  float am = fmaxf(fmaxf(red[0], red[1]), fmaxf(red[2], red[3]));
  float scale = fmaxf(am, 1e-8f) / QMAXF;
  if (threadIdx.x == 0) wsc[row] = scale;
#pragma unroll
  for (int i = 0; i < 4; i++){
    union { _Float16 h[4]; uint2 u; } pk;
    pk.h[0] = (_Float16)q8(v[i].x, scale);
    pk.h[1] = (_Float16)q8(v[i].y, scale);
    pk.h[2] = (_Float16)q8(v[i].z, scale);
    pk.h[3] = (_Float16)q8(v[i].w, scale);
    ((uint2*)dst)[threadIdx.x + i * 256] = pk.u;
  }
}

// RoPE in-place on Y (q: heads 0..31, k: heads 32..39) + per-block partials
__global__ __launch_bounds__(256) void k_rope(
    float* __restrict__ Y, const float* __restrict__ cosb,
    const float* __restrict__ sinb,
    float* __restrict__ qpart, float* __restrict__ kpart)
{
  int idx = blockIdx.x * 256 + threadIdx.x;   // 2048*40*64 total
  int s = idx / (40 * 64);
  int rem = idx - s * 40 * 64;
  int head = rem >> 6;        // wave-uniform (64 threads per head slot)
  int d = rem & 63;
  size_t base = (size_t)s * 6144 + (head < 32 ? head * 128 : 4096 + (head - 32) * 128);
  float x1 = Y[base + d], x2 = Y[base + d + 64];
  float c1 = cosb[s * 128 + d],      s1 = sinb[s * 128 + d];
  float c2 = cosb[s * 128 + d + 64], s2 = sinb[s * 128 + d + 64];
  float o1 = x1 * c1 - x2 * s1;
  float o2 = x2 * c2 + x1 * s2;
  Y[base + d] = o1; Y[base + d + 64] = o2;
  float m = wave_max64(fmaxf(fabsf(o1), fabsf(o2)));
  __shared__ float wmax[4]; __shared__ int wisq[4];
  int wid = threadIdx.x >> 6;
  if ((threadIdx.x & 63) == 0){ wmax[wid] = m; wisq[wid] = (head < 32); }
  __syncthreads();
  if (threadIdx.x == 0){
    float qm = 0.f, km = 0.f;
#pragma unroll
    for (int w = 0; w < 4; w++){
      if (wisq[w]) qm = fmaxf(qm, wmax[w]); else km = fmaxf(km, wmax[w]);
    }
    qpart[blockIdx.x] = qm; kpart[blockIdx.x] = km;
  }
}

// reduce rope partials: block 0 -> scal[1] (q), block 1 -> scal[2] (k)
__global__ __launch_bounds__(256) void k_reduce_qk(
    const float* __restrict__ qpart, const float* __restrict__ kpart,
    float* __restrict__ scal)
{
  const float* src = blockIdx.x ? kpart : qpart;
  float m = 0.f;
  for (int i = threadIdx.x; i < ROPE_BLOCKS; i += 256) m = fmaxf(m, src[i]);
  m = wave_max64(m);
  __shared__ float red[4];
  int wid = threadIdx.x >> 6;
  if ((threadIdx.x & 63) == 0) red[wid] = m;
  __syncthreads();
  if (threadIdx.x == 0)
    scal[1 + blockIdx.x] = fmaxf(fmaxf(red[0], red[1]), fmaxf(red[2], red[3]));
}

// quantize Q,K slices of Y (cols [0,5120)) -> Qh[2048][4096], Kh[2048][1024]
__global__ __launch_bounds__(256) void k_quant_qk(
    const float* __restrict__ Y, _Float16* __restrict__ Qh,
    _Float16* __restrict__ Kh, const float* __restrict__ scal)
{
  int i = blockIdx.x * 256 + threadIdx.x;       // 2048*5120/4 float4 units
  int s = i / 1280, c4 = i - s * 1280;
  int col = c4 * 4;
  float4 v = *(const float4*)(Y + (size_t)s * 6144 + col);
  float scale = fmaxf(col < 4096 ? scal[1] : scal[2], 1e-8f) / QMAXF;
  union { _Float16 h[4]; uint2 u; } pk;
  pk.h[0] = (_Float16)q8(v.x, scale);
  pk.h[1] = (_Float16)q8(v.y, scale);
  pk.h[2] = (_Float16)q8(v.z, scale);
  pk.h[3] = (_Float16)q8(v.w, scale);
  if (col < 4096) *(uint2*)(Qh + (size_t)s * 4096 + col) = pk.u;
  else            *(uint2*)(Kh + (size_t)s * 1024 + (col - 4096)) = pk.u;
}

// quantize V slice of Y with LDS-tiled transpose -> Vt[8][128][2048]
// block: 64 s x 64 d; grid (32 s-tiles, 8 kvh, 2 d-halves)
__global__ __launch_bounds__(256) void k_quant_vt(
    const float* __restrict__ Y, _Float16* __restrict__ Vt,
    const float* __restrict__ scal)
{
  __shared__ _Float16 sT[64][72];      // [d][s], stride 144 B (16B-aligned rows)
  const int s0 = blockIdx.x * 64, kvh = blockIdx.y, dh = blockIdx.z;
  const float scale = fmaxf(scal[3], 1e-8f) / QMAXF;
  const int d = threadIdx.x & 63, srow = threadIdx.x >> 6;
#pragma unroll
  for (int i = 0; i < 16; i++){
    int s = srow + i * 4;
    float v = Y[(size_t)(s0 + s) * 6144 + 5120 + kvh * 128 + dh * 64 + d];
    sT[d][s] = (_Float16)q8(v, scale);
  }
  __syncthreads();
  const int dr = threadIdx.x >> 2, j = threadIdx.x & 3;   // 64 d-rows x 4 lanes
  _Float16* dst = Vt + (size_t)kvh * HEADD * S_LEN + (size_t)(dh * 64 + dr) * S_LEN + s0 + j * 16;
  *(uint4*)(dst)     = *(const uint4*)(&sT[dr][j * 16]);
  *(uint4*)(dst + 8) = *(const uint4*)(&sT[dr][j * 16 + 8]);
}

// ---------------- GEMM: C[M][N] = (A[M][K] . B[N][K]^T) * sa * sb[n] ----------------
// m97 structure: unpadded [128][32] LDS, global_load_lds width=16, 2 barriers/iter
__global__ __launch_bounds__(256) void k_gemm_nt(
    const _Float16* __restrict__ A, const _Float16* __restrict__ B,
    const float* __restrict__ amax_a, const float* __restrict__ sb,
    float* __restrict__ C, int M, int N, int K)
{
  __shared__ _Float16 sA[128 * 32];
  __shared__ _Float16 sB[128 * 32];
  const int m0 = blockIdx.x * 128;
  const int n0 = blockIdx.y * 128;
  const int tid = threadIdx.x;
  const int w = tid >> 6, lane = tid & 63;
  const int quad = lane >> 4, l16 = lane & 15;
  const int wm = (w & 1) * 64, wn = (w >> 1) * 64;
  floatx4 acc[4][4] = {};
  // staging: wave w covers rows w*16..w*16+15 (issue 0) and +64 (issue 1);
  // lane l -> row w*16 + l/4, col (l%4)*8 halves; LDS dest = base + lane*16B
  const int srow = w * 16 + (lane >> 2);
  const int scol = (lane & 3) * 8;
  const _Float16* gA0 = A + (size_t)(m0 + srow) * K + scol;
  const _Float16* gA1 = A + (size_t)(m0 + 64 + srow) * K + scol;
  const _Float16* gB0 = B + (size_t)(n0 + srow) * K + scol;
  const _Float16* gB1 = B + (size_t)(n0 + 64 + srow) * K + scol;
  _Float16* dA0 = sA + w * 512 + lane * 8;
  _Float16* dA1 = sA + 2048 + w * 512 + lane * 8;
  _Float16* dB0 = sB + w * 512 + lane * 8;
  _Float16* dB1 = sB + 2048 + w * 512 + lane * 8;

  for (int k0 = 0; k0 < K; k0 += 32){
    __syncthreads();                       // prev iter's LDS reads done
    gload_lds16(gA0 + k0, dA0);
    gload_lds16(gA1 + k0, dA1);
    gload_lds16(gB0 + k0, dB0);
    gload_lds16(gB1 + k0, dB1);
    __syncthreads();                       // drains vmcnt before barrier
    half8 af[4], bf[4];
#pragma unroll
    for (int i = 0; i < 4; i++){
      af[i] = *(const half8*)(sA + (wm + i * 16 + l16) * 32 + quad * 8);
      bf[i] = *(const half8*)(sB + (wn + i * 16 + l16) * 32 + quad * 8);
    }
#pragma unroll
    for (int i = 0; i < 4; i++)
#pragma unroll
      for (int j = 0; j < 4; j++)
        acc[i][j] = __builtin_amdgcn_mfma_f32_16x16x32_f16(af[i], bf[j], acc[i][j], 0, 0, 0);
  }
  const float sa = fmaxf(*amax_a, 1e-8f) / QMAXF;
#pragma unroll
  for (int i = 0; i < 4; i++){
    int row = m0 + wm + i * 16 + quad * 4;
#pragma unroll
    for (int j = 0; j < 4; j++){
      int col = n0 + wn + j * 16 + l16;
      float sc2 = sa * sb[col];
#pragma unroll
      for (int rr = 0; rr < 4; rr++)
        C[(size_t)(row + rr) * N + col] = acc[i][j][rr] * sc2;
    }
  }
}

// ---------------- flash attention, exact quantized softmax ----------------
// grid (32,32): one 64-row q-tile per block, CU-balanced qb mapping.
// pass1: exact row max m and denom l (K double-buffered, 1 barrier/ktile).
// pass2: recompute S, quantize probs, PV (2 barriers/ktile, T14 prefetch).
// LDS 40960B exact -> 4 blocks/CU. All tiles 16B-chunk XOR-swizzled:
//   chunk j of row r holds source chunk (j&8)|((j^r)&7)  -> balanced-8-way b128.
__global__ __launch_bounds__(256, 4) void k_attn(
    const _Float16* __restrict__ Qh,  // [2048][4096]  (s, h*128+d) int-f16
    const _Float16* __restrict__ Kh,  // [2048][1024]  (s, kvh*128+d)
    const _Float16* __restrict__ Vt,  // [8][128][2048] (kvh, d, s)
    const float* __restrict__ scal,
    float* __restrict__ AO)           // [2048][4096] fp32
{
  // CU-balance: with 4 blocks/CU fully resident and stride-256 co-residency,
  // a CU's 4 blocks see qb in {a, 31-a, (a+16)&31, 31-((a+16)&31)} -> 66 units.
  const int jj = blockIdx.y >> 3;
  const int aa = (jj & 2) ? (int)((blockIdx.x + 16) & 31) : (int)blockIdx.x;
  const int qb = (jj & 1) ? (31 - aa) : aa;
  const int h   = blockIdx.y;    // 0..31
  const int kvh = h >> 2;        // GQA groups=4
  const int tid = threadIdx.x;
  const int wid = tid >> 6, lane = tid & 63;
  const int quad = lane >> 4, l16 = lane & 15;

  __shared__ _Float16 sKV[2][8192];   // pass1: K dbuf [64][128]; pass2: [0]=K [64][128], [1]=V [128][64]
  __shared__ _Float16 sP[4][1024];    // per-wave P tile [16][64], swizzled

  const float s_q = fmaxf(scal[1], 1e-8f) / QMAXF;
  const float s_k = fmaxf(scal[2], 1e-8f) / QMAXF;
  const float s_v = fmaxf(scal[3], 1e-8f) / QMAXF;
  const float qkscale = s_q * s_k * 0.08838834764831845f;  // * HD^-0.5
  const float osc = s_v * (1.0f / QMAXF);

  // ---- staging / read offset tables (halves) ----
  const int r   = tid >> 2, seg = tid & 3;      // K staging: tile row r, 64B seg
  int kst[4];
#pragma unroll
  for (int i = 0; i < 4; i++){
    int c = seg * 4 + i;                        // source chunk (16 per 256B row)
    kst[i] = r * 128 + ((c & 8) | ((c ^ (r & 7)) & 7)) * 8;
  }
  const int vr = tid >> 1, vh = tid & 1;        // V staging: d-row vr, 64B half
  int vst[4];
#pragma unroll
  for (int i = 0; i < 4; i++){
    int c = vh * 4 + i;                         // source chunk (8 per 128B row)
    vst[i] = vr * 64 + ((c ^ (vr & 7)) & 7) * 8;
  }
  int krd[4];                                   // QK read: row = nt*16+l16 (row&7 == l16&7)
#pragma unroll
  for (int kk = 0; kk < 4; kk++){
    int c = kk * 4 + quad;
    krd[kk] = l16 * 128 + ((c & 8) | ((c ^ (l16 & 7)) & 7)) * 8;
  }
  const int vrd0 = l16 * 64 + ((quad       ^ (l16 & 7)) & 7) * 8;  // PV V read b0
  const int vrd1 = l16 * 64 + (((quad ^ 4) ^ (l16 & 7)) & 7) * 8;  // b1 (chunk quad+4)

  const _Float16* gK0 = Kh + (size_t)r * 1024 + (size_t)kvh * 128 + seg * 32;
  const _Float16* gV0 = Vt + (size_t)kvh * (HEADD * S_LEN) + (size_t)vr * S_LEN + vh * 32;

  const int qrow = qb * 64 + wid * 16 + l16;
  half8 qf[4];
#pragma unroll
  for (int kk = 0; kk < 4; kk++)
    qf[kk] = *(const half8*)(Qh + (size_t)qrow * 4096 + h * 128 + kk * 32 + quad * 8);
  const int q_of_reg = qb * 64 + wid * 16 + quad * 4;   // + rr = global q row

  float mrow[4], lrow[4];
#pragma unroll
  for (int rr = 0; rr < 4; rr++){ mrow[rr] = -__builtin_inff(); lrow[rr] = 0.f; }

  // ---- pass 1: exact row max + denominator (K double-buffered, 1 barrier/iter) ----
  {
    const uint4* g = (const uint4*)gK0;
    uint4 t0 = g[0], t1 = g[1], t2 = g[2], t3 = g[3];
    _Float16* b = sKV[0];
    *(uint4*)(b + kst[0]) = t0; *(uint4*)(b + kst[1]) = t1;
    *(uint4*)(b + kst[2]) = t2; *(uint4*)(b + kst[3]) = t3;
  }
  __syncthreads();

  for (int kt = 0; kt <= qb; ++kt){
    uint4 t0, t1, t2, t3;
    if (kt < qb){                               // prefetch next tile (hides under MFMA)
      const uint4* g = (const uint4*)(gK0 + (size_t)(kt + 1) * 65536);
      t0 = g[0]; t1 = g[1]; t2 = g[2]; t3 = g[3];
    }
    const _Float16* kb = sKV[kt & 1];
    float sv[4][4];
    const bool diag = (kt == qb);               // wave-uniform
    __builtin_amdgcn_s_setprio(1);
#pragma unroll
    for (int nt = 0; nt < 4; nt++){
      floatx4 c = {};
#pragma unroll
      for (int kk = 0; kk < 4; kk++){
        half8 bf = *(const half8*)(kb + nt * 2048 + krd[kk]);
        c = __builtin_amdgcn_mfma_f32_16x16x32_f16(qf[kk], bf, c, 0, 0, 0);
      }
      if (diag){
        int kpos = kt * 64 + nt * 16 + l16;
#pragma unroll
        for (int rr = 0; rr < 4; rr++)
          sv[nt][rr] = (kpos <= q_of_reg + rr) ? c[rr] * qkscale : -__builtin_inff();
      } else {
#pragma unroll
        for (int rr = 0; rr < 4; rr++) sv[nt][rr] = c[rr] * qkscale;
      }
    }
    __builtin_amdgcn_s_setprio(0);
    if (kt < qb){                               // store next tile into other buffer
      _Float16* b = sKV[(kt + 1) & 1];
      *(uint4*)(b + kst[0]) = t0; *(uint4*)(b + kst[1]) = t1;
      *(uint4*)(b + kst[2]) = t2; *(uint4*)(b + kst[3]) = t3;
    }
#pragma unroll
    for (int rr = 0; rr < 4; rr++){
      float lmax = fmaxf(fmaxf(sv[0][rr], sv[1][rr]), fmaxf(sv[2][rr], sv[3][rr]));
      float tmax = grp16_max(lmax);
      float mnew = fmaxf(mrow[rr], tmax);
      float lsum = 0.f;
#pragma unroll
      for (int nt = 0; nt < 4; nt++) lsum += __expf(sv[nt][rr] - mnew);
      lsum = grp16_sum(lsum);
      lrow[rr] = lrow[rr] * __expf(mrow[rr] - mnew) + lsum;
      mrow[rr] = mnew;
    }
    __syncthreads();
  }

  float il[4];   // 127 / l  (rcp: ~1ulp, quant boundary noise only)
#pragma unroll
  for (int rr = 0; rr < 4; rr++) il[rr] = QMAXF * __builtin_amdgcn_rcpf(lrow[rr]);

  // ---- pass 2: recompute, quantize probs, PV ----
  floatx4 accO[8] = {};
  _Float16* sKb = sKV[0];
  _Float16* sVb = sKV[1];
  _Float16* sPw = sP[wid];

  uint4 t0, t1, t2, t3, u0, u1, u2, u3;
  {
    const uint4* g  = (const uint4*)gK0;
    t0 = g[0];  t1 = g[1];  t2 = g[2];  t3 = g[3];
    const uint4* gv = (const uint4*)gV0;
    u0 = gv[0]; u1 = gv[1]; u2 = gv[2]; u3 = gv[3];
  }
  for (int kt = 0; kt <= qb; ++kt){
    __syncthreads();                            // all waves done reading sKb/sVb
    *(uint4*)(sKb + kst[0]) = t0; *(uint4*)(sKb + kst[1]) = t1;
    *(uint4*)(sKb + kst[2]) = t2; *(uint4*)(sKb + kst[3]) = t3;
    *(uint4*)(sVb + vst[0]) = u0; *(uint4*)(sVb + vst[1]) = u1;
    *(uint4*)(sVb + vst[2]) = u2; *(uint4*)(sVb + vst[3]) = u3;
    __syncthreads();
    const bool diag = (kt == qb);
    __builtin_amdgcn_s_setprio(1);
#pragma unroll
    for (int nt = 0; nt < 4; nt++){
      floatx4 c = {};
#pragma unroll
      for (int kk = 0; kk < 4; kk++){
        half8 bf = *(const half8*)(sKb + nt * 2048 + krd[kk]);
        c = __builtin_amdgcn_mfma_f32_16x16x32_f16(qf[kk], bf, c, 0, 0, 0);
      }
      int kpos = kt * 64 + nt * 16 + l16;
#pragma unroll
      for (int rr = 0; rr < 4; rr++){
        float pq = fminf(rintf(__expf(c[rr] * qkscale - mrow[rr]) * il[rr]), 127.f);
        if (diag && kpos > q_of_reg + rr) pq = 0.f;
        int row = quad * 4 + rr;
        sPw[row * 64 + ((nt * 2 + (l16 >> 3)) ^ (row & 7)) * 8 + (l16 & 7)] = (_Float16)pq;
      }
    }
    __builtin_amdgcn_s_setprio(0);
    if (kt < qb){                               // T14: issue next-tile loads, hide under PV
      const uint4* g  = (const uint4*)(gK0 + (size_t)(kt + 1) * 65536);
      t0 = g[0];  t1 = g[1];  t2 = g[2];  t3 = g[3];
      const uint4* gv = (const uint4*)(gV0 + (size_t)(kt + 1) * 64);
      u0 = gv[0]; u1 = gv[1]; u2 = gv[2]; u3 = gv[3];
    }
    // sP is wave-private: intra-wave lgkmcnt ordering, no barrier needed
    half8 pf0 = *(const half8*)(sPw + vrd0);    // P read, same swizzle form as V
    half8 pf1 = *(const half8*)(sPw + vrd1);
    __builtin_amdgcn_s_setprio(1);
#pragma unroll
    for (int dt = 0; dt < 8; dt++){
      half8 b0 = *(const half8*)(sVb + dt * 1024 + vrd0);
      half8 b1 = *(const half8*)(sVb + dt * 1024 + vrd1);
      accO[dt] = __builtin_amdgcn_mfma_f32_16x16x32_f16(pf0, b0, accO[dt], 0, 0, 0);
      accO[dt] = __builtin_amdgcn_mfma_f32_16x16x32_f16(pf1, b1, accO[dt], 0, 0, 0);
    }
    __builtin_amdgcn_s_setprio(0);
  }

#pragma unroll
  for (int dt = 0; dt < 8; dt++){
    int col = h * 128 + dt * 16 + l16;
#pragma unroll
    for (int rr = 0; rr < 4; rr++)
      AO[(size_t)(q_of_reg + rr) * 4096 + col] = accO[dt][rr] * osc;
  }
}

// ---------------- launch ----------------
extern "C" void kernel_launch(void* const* d_in, const int* in_sizes, int n_in,
                              void* d_out, int out_size, void* d_ws, size_t ws_size,
                              hipStream_t stream)
{
  const float* hidden = (const float*)d_in[0];
  // d_in[1] attention_mask: deterministic causal -> computed analytically
  const float* cosb = (const float*)d_in[2];
  const float* sinb = (const float*)d_in[3];
  const float* wq = (const float*)d_in[4];
  const float* wk = (const float*)d_in[5];
  const float* wv = (const float*)d_in[6];
  const float* wo = (const float*)d_in[7];
  float* out = (float*)d_out;

  char* ws = (char*)d_ws;
  size_t off = 0;
  auto alloc = [&](size_t bytes){ size_t o = off; off += (bytes + 255) & ~(size_t)255; return o; };
  float*    scal  = (float*)   (ws + alloc(64));                       // amax: x,q,k,v,ao
  float*    wsc   = (float*)   (ws + alloc(10240 * 4));                // per-row weight scales
  float*    qpart = (float*)   (ws + alloc(ROPE_BLOCKS * 4));
  float*    kpart = (float*)   (ws + alloc(ROPE_BLOCKS * 4));
  _Float16* Wall  = (_Float16*)(ws + alloc((size_t)6144 * 4096 * 2));  // wq|wk|wv int-f16
  _Float16* Wo    = (_Float16*)(ws + alloc((size_t)4096 * 4096 * 2));
  _Float16* Xq    = (_Float16*)(ws + alloc((size_t)2048 * 4096 * 2));
  float*    Y     = (float*)   (ws + alloc((size_t)2048 * 6144 * 4));  // qkv proj fp32
  // aliases (lifetimes disjoint): total ws ~151 MB
  _Float16* Qh  = Xq;                                   // written after GEMM1 read of Xq
  _Float16* Kh  = Wall;                                 // written after GEMM1 read of Wall
  _Float16* Vt  = Wall + (size_t)2048 * 1024;
  float*    AO  = Y;                                    // written after Y consumed
  _Float16* AOq = (_Float16*)((char*)Y + (size_t)2048 * 4096 * 4);

  unsigned* su = (unsigned*)scal;

  k_init<<<dim3(1), dim3(64), 0, stream>>>(scal);
  k_quant_w<<<dim3(10240), dim3(256), 0, stream>>>(wq, wk, wv, wo, Wall, Wo, wsc);
  k_amax<<<dim3(256), dim3(256), 0, stream>>>(hidden, (size_t)(2048 * 4096 / 4), su + 0);
  k_quant<<<dim3(2048), dim3(256), 0, stream>>>(hidden, Xq, (size_t)(2048 * 4096 / 4), scal + 0);
  k_gemm_nt<<<dim3(16, 48), dim3(256), 0, stream>>>(Xq, Wall, scal + 0, wsc, Y, 2048, 6144, 4096);
  k_rope<<<dim3(ROPE_BLOCKS), dim3(256), 0, stream>>>(Y, cosb, sinb, qpart, kpart);
  k_reduce_qk<<<dim3(2), dim3(256), 0, stream>>>(qpart, kpart, scal);
  k_amax_v<<<dim3(256), dim3(256), 0, stream>>>(Y, su + 3);
  k_quant_qk<<<dim3(10240), dim3(256), 0, stream>>>(Y, Qh, Kh, scal);
  k_quant_vt<<<dim3(32, 8, 2), dim3(256), 0, stream>>>(Y, Vt, scal);
  k_attn<<<dim3(32, 32), dim3(256), 0, stream>>>(Qh, Kh, Vt, scal, AO);
  k_amax<<<dim3(256), dim3(256), 0, stream>>>(AO, (size_t)(2048 * 4096 / 4), su + 4);
  k_quant<<<dim3(2048), dim3(256), 0, stream>>>(AO, AOq, (size_t)(2048 * 4096 / 4), scal + 4);
  k_gemm_nt<<<dim3(16, 32), dim3(256), 0, stream>>>(AOq, Wo, scal + 4, wsc + 6144, out, 2048, 4096, 4096);
}

// Round 3
// 679.880 us; speedup vs baseline: 1.0818x; 1.0818x over previous
//
#include <hip/hip_runtime.h>
#include <cstdint>
#include <cstddef>

// QuantLlamaAttention: int8 fake-quant Llama attention block, MI355X (gfx950).
// All matmuls carry quantized INTEGER values in _Float16 (exact for |v|<=2048)
// through mfma_f32_16x16x32_f16, fp32 accumulate, scales applied in epilogue.
// softmax prob amax is exactly 1.0 (causal row 0) -> static prob scale 1/127,
// enabling a two-pass flash attention with exact quantization (no S matrix).
//
// R1: same-address atomicMax serialization -> block partials / 1 atomic per block.
// R2: k_attn 368us: __expf, rcp prob scale, diag-only masking, q-tile pairing,
//     GEMM k-loop -> m97-style global_load_lds width=16.
// R3/R4: k_attn 177us REGRESSION: __launch_bounds__(256,4) capped VGPR at 64 ->
//     spills (WRITE_SIZE 33->107MB). Structure (40KB LDS, swizzle, 1-barrier
//     pass1, CU-balanced qb map) kept.
// R5: spill fix: K/V staging via global_load_lds with PRE-SWIZZLED per-lane
//     global addresses (linear LDS dest, same involution on read side) ->
//     -32 prefetch VGPRs, no staging ds_writes; __launch_bounds__(256,2)
//     (observed cap is one bucket tighter than documented formula).
//     pass1: K dbuf, DMA for kt+1 issued after the single barrier (flies under
//     MFMA). pass2: single-buf K+V, 2 barriers, both DMAs issued together.

#define S_LEN   2048
#define HDIM    4096
#define NHEADS  32
#define NKVH    8
#define HEADD   128
#define QMAXF   127.0f
#define ROPE_BLOCKS 20480

typedef _Float16 half8  __attribute__((ext_vector_type(8)));
typedef float    floatx4 __attribute__((ext_vector_type(4)));

// ---------------- helpers ----------------
__device__ __forceinline__ float wave_max64(float v){
#pragma unroll
  for (int off = 32; off > 0; off >>= 1) v = fmaxf(v, __shfl_xor(v, off));
  return v;
}
__device__ __forceinline__ float grp16_max(float v){
#pragma unroll
  for (int off = 8; off > 0; off >>= 1) v = fmaxf(v, __shfl_xor(v, off));
  return v;
}
__device__ __forceinline__ float grp16_sum(float v){
#pragma unroll
  for (int off = 8; off > 0; off >>= 1) v += __shfl_xor(v, off);
  return v;
}
__device__ __forceinline__ void atomic_max_f(unsigned* p, float v){
  atomicMax(p, __float_as_uint(v));   // v >= 0: uint bits order-preserving
}
__device__ __forceinline__ float q8(float x, float scale){
  return fminf(fmaxf(rintf(x / scale), -128.f), 127.f);  // rintf = half-even, matches jnp.round
}
// async global->LDS, 16B per lane. HW: LDS dest = wave-uniform base + lane*16.
__device__ __forceinline__ void gload_lds16(const _Float16* g, _Float16* l){
  __builtin_amdgcn_global_load_lds((const __attribute__((address_space(1))) void*)g,
                                   (__attribute__((address_space(3))) void*)l, 16, 0, 0);
}

// block-level max of per-wave maxima (256 threads = 4 waves), then ONE atomic
__device__ __forceinline__ void block_atomic_max(float m, unsigned* out){
  m = wave_max64(m);
  __shared__ float red[4];
  int wid = threadIdx.x >> 6;
  if ((threadIdx.x & 63) == 0) red[wid] = m;
  __syncthreads();
  if (threadIdx.x == 0)
    atomic_max_f(out, fmaxf(fmaxf(red[0], red[1]), fmaxf(red[2], red[3])));
}

// ---------------- tiny kernels ----------------
__global__ void k_init(float* scal){ if (threadIdx.x < 16) scal[threadIdx.x] = 0.0f; }

__global__ void k_amax(const float* __restrict__ x, size_t n4, unsigned* __restrict__ out){
  size_t i = (size_t)blockIdx.x * blockDim.x + threadIdx.x;
  size_t stride = (size_t)gridDim.x * blockDim.x;
  float m = 0.f;
  for (; i < n4; i += stride){
    float4 v = ((const float4*)x)[i];
    m = fmaxf(m, fmaxf(fmaxf(fabsf(v.x), fabsf(v.y)), fmaxf(fabsf(v.z), fabsf(v.w))));
  }
  block_atomic_max(m, out);
}

// amax over the V slice (cols [5120,6144)) of Y[2048][6144]
__global__ void k_amax_v(const float* __restrict__ Y, unsigned* __restrict__ out){
  size_t i = (size_t)blockIdx.x * blockDim.x + threadIdx.x;
  size_t stride = (size_t)gridDim.x * blockDim.x;
  float m = 0.f;
  for (size_t e = i; e < (size_t)S_LEN * 1024; e += stride){
    size_t s = e >> 10; int c = (int)(e & 1023);
    m = fmaxf(m, fabsf(Y[s * 6144 + 5120 + c]));
  }
  block_atomic_max(m, out);
}

// per-tensor quantize fp32 -> integer-valued f16
__global__ void k_quant(const float* __restrict__ x, _Float16* __restrict__ q,
                        size_t n4, const float* __restrict__ amax){
  float scale = fmaxf(*amax, 1e-8f) / QMAXF;
  size_t i = (size_t)blockIdx.x * blockDim.x + threadIdx.x;
  size_t stride = (size_t)gridDim.x * blockDim.x;
  for (; i < n4; i += stride){
    float4 v = ((const float4*)x)[i];
    union { _Float16 h[4]; uint2 u; } pk;
    pk.h[0] = (_Float16)q8(v.x, scale);
    pk.h[1] = (_Float16)q8(v.y, scale);
    pk.h[2] = (_Float16)q8(v.z, scale);
    pk.h[3] = (_Float16)q8(v.w, scale);
    ((uint2*)q)[i] = pk.u;
  }
}

// per-row weight quantization: rows 0..6143 -> Wall (wq|wk|wv), 6144..10239 -> Wo
__global__ __launch_bounds__(256) void k_quant_w(
    const float* __restrict__ wq, const float* __restrict__ wk,
    const float* __restrict__ wv, const float* __restrict__ wo,
    _Float16* __restrict__ Wall, _Float16* __restrict__ Wo,
    float* __restrict__ wsc)
{
  int row = blockIdx.x;
  const float* src; _Float16* dst;
  if (row < 4096)      { src = wq + (size_t)row * HDIM;          dst = Wall + (size_t)row * HDIM; }
  else if (row < 5120) { src = wk + (size_t)(row - 4096) * HDIM; dst = Wall + (size_t)row * HDIM; }
  else if (row < 6144) { src = wv + (size_t)(row - 5120) * HDIM; dst = Wall + (size_t)row * HDIM; }
  else                 { src = wo + (size_t)(row - 6144) * HDIM; dst = Wo + (size_t)(row - 6144) * HDIM; }
  float4 v[4]; float m = 0.f;
#pragma unroll
  for (int i = 0; i < 4; i++){
    v[i] = ((const float4*)src)[threadIdx.x + i * 256];
    m = fmaxf(m, fmaxf(fmaxf(fabsf(v[i].x), fabsf(v[i].y)), fmaxf(fabsf(v[i].z), fabsf(v[i].w))));
  }
  m = wave_max64(m);
  __shared__ float red[4];
  int wid = threadIdx.x >> 6;
  if ((threadIdx.x & 63) == 0) red[wid] = m;
  __syncthreads();
  float am = fmaxf(fmaxf(red[0], red[1]), fmaxf(red[2], red[3]));
  float scale = fmaxf(am, 1e-8f) / QMAXF;
  if (threadIdx.x == 0) wsc[row] = scale;
#pragma unroll
  for (int i = 0; i < 4; i++){
    union { _Float16 h[4]; uint2 u; } pk;
    pk.h[0] = (_Float16)q8(v[i].x, scale);
    pk.h[1] = (_Float16)q8(v[i].y, scale);
    pk.h[2] = (_Float16)q8(v[i].z, scale);
    pk.h[3] = (_Float16)q8(v[i].w, scale);
    ((uint2*)dst)[threadIdx.x + i * 256] = pk.u;
  }
}

// RoPE in-place on Y (q: heads 0..31, k: heads 32..39) + per-block partials
__global__ __launch_bounds__(256) void k_rope(
    float* __restrict__ Y, const float* __restrict__ cosb,
    const float* __restrict__ sinb,
    float* __restrict__ qpart, float* __restrict__ kpart)
{
  int idx = blockIdx.x * 256 + threadIdx.x;   // 2048*40*64 total
  int s = idx / (40 * 64);
  int rem = idx - s * 40 * 64;
  int head = rem >> 6;        // wave-uniform (64 threads per head slot)
  int d = rem & 63;
  size_t base = (size_t)s * 6144 + (head < 32 ? head * 128 : 4096 + (head - 32) * 128);
  float x1 = Y[base + d], x2 = Y[base + d + 64];
  float c1 = cosb[s * 128 + d],      s1 = sinb[s * 128 + d];
  float c2 = cosb[s * 128 + d + 64], s2 = sinb[s * 128 + d + 64];
  float o1 = x1 * c1 - x2 * s1;
  float o2 = x2 * c2 + x1 * s2;
  Y[base + d] = o1; Y[base + d + 64] = o2;
  float m = wave_max64(fmaxf(fabsf(o1), fabsf(o2)));
  __shared__ float wmax[4]; __shared__ int wisq[4];
  int wid = threadIdx.x >> 6;
  if ((threadIdx.x & 63) == 0){ wmax[wid] = m; wisq[wid] = (head < 32); }
  __syncthreads();
  if (threadIdx.x == 0){
    float qm = 0.f, km = 0.f;
#pragma unroll
    for (int w = 0; w < 4; w++){
      if (wisq[w]) qm = fmaxf(qm, wmax[w]); else km = fmaxf(km, wmax[w]);
    }
    qpart[blockIdx.x] = qm; kpart[blockIdx.x] = km;
  }
}

// reduce rope partials: block 0 -> scal[1] (q), block 1 -> scal[2] (k)
__global__ __launch_bounds__(256) void k_reduce_qk(
    const float* __restrict__ qpart, const float* __restrict__ kpart,
    float* __restrict__ scal)
{
  const float* src = blockIdx.x ? kpart : qpart;
  float m = 0.f;
  for (int i = threadIdx.x; i < ROPE_BLOCKS; i += 256) m = fmaxf(m, src[i]);
  m = wave_max64(m);
  __shared__ float red[4];
  int wid = threadIdx.x >> 6;
  if ((threadIdx.x & 63) == 0) red[wid] = m;
  __syncthreads();
  if (threadIdx.x == 0)
    scal[1 + blockIdx.x] = fmaxf(fmaxf(red[0], red[1]), fmaxf(red[2], red[3]));
}

// quantize Q,K slices of Y (cols [0,5120)) -> Qh[2048][4096], Kh[2048][1024]
__global__ __launch_bounds__(256) void k_quant_qk(
    const float* __restrict__ Y, _Float16* __restrict__ Qh,
    _Float16* __restrict__ Kh, const float* __restrict__ scal)
{
  int i = blockIdx.x * 256 + threadIdx.x;       // 2048*5120/4 float4 units
  int s = i / 1280, c4 = i - s * 1280;
  int col = c4 * 4;
  float4 v = *(const float4*)(Y + (size_t)s * 6144 + col);
  float scale = fmaxf(col < 4096 ? scal[1] : scal[2], 1e-8f) / QMAXF;
  union { _Float16 h[4]; uint2 u; } pk;
  pk.h[0] = (_Float16)q8(v.x, scale);
  pk.h[1] = (_Float16)q8(v.y, scale);
  pk.h[2] = (_Float16)q8(v.z, scale);
  pk.h[3] = (_Float16)q8(v.w, scale);
  if (col < 4096) *(uint2*)(Qh + (size_t)s * 4096 + col) = pk.u;
  else            *(uint2*)(Kh + (size_t)s * 1024 + (col - 4096)) = pk.u;
}

// quantize V slice of Y with LDS-tiled transpose -> Vt[8][128][2048]
// block: 64 s x 64 d; grid (32 s-tiles, 8 kvh, 2 d-halves)
__global__ __launch_bounds__(256) void k_quant_vt(
    const float* __restrict__ Y, _Float16* __restrict__ Vt,
    const float* __restrict__ scal)
{
  __shared__ _Float16 sT[64][72];      // [d][s], stride 144 B (16B-aligned rows)
  const int s0 = blockIdx.x * 64, kvh = blockIdx.y, dh = blockIdx.z;
  const float scale = fmaxf(scal[3], 1e-8f) / QMAXF;
  const int d = threadIdx.x & 63, srow = threadIdx.x >> 6;
#pragma unroll
  for (int i = 0; i < 16; i++){
    int s = srow + i * 4;
    float v = Y[(size_t)(s0 + s) * 6144 + 5120 + kvh * 128 + dh * 64 + d];
    sT[d][s] = (_Float16)q8(v, scale);
  }
  __syncthreads();
  const int dr = threadIdx.x >> 2, j = threadIdx.x & 3;   // 64 d-rows x 4 lanes
  _Float16* dst = Vt + (size_t)kvh * HEADD * S_LEN + (size_t)(dh * 64 + dr) * S_LEN + s0 + j * 16;
  *(uint4*)(dst)     = *(const uint4*)(&sT[dr][j * 16]);
  *(uint4*)(dst + 8) = *(const uint4*)(&sT[dr][j * 16 + 8]);
}

// ---------------- GEMM: C[M][N] = (A[M][K] . B[N][K]^T) * sa * sb[n] ----------------
// m97 structure: unpadded [128][32] LDS, global_load_lds width=16, 2 barriers/iter
__global__ __launch_bounds__(256) void k_gemm_nt(
    const _Float16* __restrict__ A, const _Float16* __restrict__ B,
    const float* __restrict__ amax_a, const float* __restrict__ sb,
    float* __restrict__ C, int M, int N, int K)
{
  __shared__ _Float16 sA[128 * 32];
  __shared__ _Float16 sB[128 * 32];
  const int m0 = blockIdx.x * 128;
  const int n0 = blockIdx.y * 128;
  const int tid = threadIdx.x;
  const int w = tid >> 6, lane = tid & 63;
  const int quad = lane >> 4, l16 = lane & 15;
  const int wm = (w & 1) * 64, wn = (w >> 1) * 64;
  floatx4 acc[4][4] = {};
  // staging: wave w covers rows w*16..w*16+15 (issue 0) and +64 (issue 1);
  // lane l -> row w*16 + l/4, col (l%4)*8 halves; LDS dest = base + lane*16B
  const int srow = w * 16 + (lane >> 2);
  const int scol = (lane & 3) * 8;
  const _Float16* gA0 = A + (size_t)(m0 + srow) * K + scol;
  const _Float16* gA1 = A + (size_t)(m0 + 64 + srow) * K + scol;
  const _Float16* gB0 = B + (size_t)(n0 + srow) * K + scol;
  const _Float16* gB1 = B + (size_t)(n0 + 64 + srow) * K + scol;
  _Float16* dA0 = sA + w * 512 + lane * 8;
  _Float16* dA1 = sA + 2048 + w * 512 + lane * 8;
  _Float16* dB0 = sB + w * 512 + lane * 8;
  _Float16* dB1 = sB + 2048 + w * 512 + lane * 8;

  for (int k0 = 0; k0 < K; k0 += 32){
    __syncthreads();                       // prev iter's LDS reads done
    gload_lds16(gA0 + k0, dA0);
    gload_lds16(gA1 + k0, dA1);
    gload_lds16(gB0 + k0, dB0);
    gload_lds16(gB1 + k0, dB1);
    __syncthreads();                       // drains vmcnt before barrier
    half8 af[4], bf[4];
#pragma unroll
    for (int i = 0; i < 4; i++){
      af[i] = *(const half8*)(sA + (wm + i * 16 + l16) * 32 + quad * 8);
      bf[i] = *(const half8*)(sB + (wn + i * 16 + l16) * 32 + quad * 8);
    }
#pragma unroll
    for (int i = 0; i < 4; i++)
#pragma unroll
      for (int j = 0; j < 4; j++)
        acc[i][j] = __builtin_amdgcn_mfma_f32_16x16x32_f16(af[i], bf[j], acc[i][j], 0, 0, 0);
  }
  const float sa = fmaxf(*amax_a, 1e-8f) / QMAXF;
#pragma unroll
  for (int i = 0; i < 4; i++){
    int row = m0 + wm + i * 16 + quad * 4;
#pragma unroll
    for (int j = 0; j < 4; j++){
      int col = n0 + wn + j * 16 + l16;
      float sc2 = sa * sb[col];
#pragma unroll
      for (int rr = 0; rr < 4; rr++)
        C[(size_t)(row + rr) * N + col] = acc[i][j][rr] * sc2;
    }
  }
}

// ---------------- flash attention, exact quantized softmax ----------------
// grid (32,32): one 64-row q-tile per block, CU-balanced qb mapping.
// LDS 40960B exact -> 4 blocks/CU. K/V staged via global_load_lds with
// PRE-SWIZZLED per-lane global addresses (linear LDS dest); reads use the
// same 16B-chunk involution: pos p of row r holds source chunk
// (p&8)|((p^(r&7))&7)  -> balanced-8-way conflict-free ds_read_b128.
// pass1: K double-buffered, DMA for kt+1 issued after the single barrier.
// pass2: single-buffered K+V, 2 barriers/iter, both DMAs issued together.
__global__ __launch_bounds__(256, 2) void k_attn(
    const _Float16* __restrict__ Qh,  // [2048][4096]  (s, h*128+d) int-f16
    const _Float16* __restrict__ Kh,  // [2048][1024]  (s, kvh*128+d)
    const _Float16* __restrict__ Vt,  // [8][128][2048] (kvh, d, s)
    const float* __restrict__ scal,
    float* __restrict__ AO)           // [2048][4096] fp32
{
  // CU-balance: with 4 blocks/CU resident under stride-256 co-residency,
  // a CU's 4 blocks see qb in {a, 31-a, (a+16)&31, 31-((a+16)&31)} -> 66 units.
  const int jj = blockIdx.y >> 3;
  const int aa = (jj & 2) ? (int)((blockIdx.x + 16) & 31) : (int)blockIdx.x;
  const int qb = (jj & 1) ? (31 - aa) : aa;
  const int h   = blockIdx.y;    // 0..31
  const int kvh = h >> 2;        // GQA groups=4
  const int tid = threadIdx.x;
  const int wid = tid >> 6, lane = tid & 63;
  const int quad = lane >> 4, l16 = lane & 15;

  __shared__ _Float16 sKV[2][8192];   // pass1: K dbuf [64][128]; pass2: [0]=K, [1]=V [128][64]
  __shared__ _Float16 sP[4][1024];    // per-wave P tile [16][64], swizzled

  const float s_q = fmaxf(scal[1], 1e-8f) / QMAXF;
  const float s_k = fmaxf(scal[2], 1e-8f) / QMAXF;
  const float s_v = fmaxf(scal[3], 1e-8f) / QMAXF;
  const float qkscale = s_q * s_k * 0.08838834764831845f;  // * HD^-0.5
  const float osc = s_v * (1.0f / QMAXF);

  // ---- K staging (global_load_lds, pre-swizzled source) ----
  // inst i, wave w, lane -> LDS 16B slot (i*256 + w*64 + lane):
  //   tile row = i*16 + w*4 + quad, chunk pos p = l16,
  //   source chunk sch = (p&8)|((p^(row&7))&7), row&7 = (w*4+quad)&7.
  const int srow7 = (wid * 4 + quad) & 7;
  const int sch   = (l16 & 8) | ((l16 ^ srow7) & 7);
  const _Float16* gKs = Kh + (size_t)(wid * 4 + quad) * 1024 + (size_t)kvh * 128 + sch * 8;
  // ---- V staging ----
  // inst i, wave w, lane -> slot (i*256 + w*64 + lane):
  //   d-row = i*32 + w*8 + (lane>>3), pos p = lane&7, src chunk = p^(row&7), row&7 = lane>>3.
  const int vrg = lane >> 3, vp = lane & 7;
  const _Float16* gVs = Vt + (size_t)kvh * (HEADD * S_LEN)
                           + (size_t)(wid * 8 + vrg) * S_LEN + ((vp ^ vrg) & 7) * 8;

  // ---- swizzled read offsets ----
  int krd[4];                                   // QK read: row = nt*16+l16 (row&7 == l16&7)
#pragma unroll
  for (int kk = 0; kk < 4; kk++){
    int c = kk * 4 + quad;
    krd[kk] = l16 * 128 + ((c & 8) | ((c ^ (l16 & 7)) & 7)) * 8;
  }
  const int vrd0 = l16 * 64 + ((quad       ^ (l16 & 7)) & 7) * 8;  // PV V read b0
  const int vrd1 = l16 * 64 + (((quad ^ 4) ^ (l16 & 7)) & 7) * 8;  // b1 (chunk quad+4)

  const int qrow = qb * 64 + wid * 16 + l16;
  half8 qf[4];
#pragma unroll
  for (int kk = 0; kk < 4; kk++)
    qf[kk] = *(const half8*)(Qh + (size_t)qrow * 4096 + h * 128 + kk * 32 + quad * 8);
  const int q_of_reg = qb * 64 + wid * 16 + quad * 4;   // + rr = global q row

  float mrow[4], lrow[4];
#pragma unroll
  for (int rr = 0; rr < 4; rr++){ mrow[rr] = -__builtin_inff(); lrow[rr] = 0.f; }

  // DMA helpers: dst = per-wave region base (HW adds lane*16B); 4 insts cover a 16KB tile
  auto stage_k = [&](int kt, _Float16* buf){
    const _Float16* g = gKs + (size_t)kt * 65536;
    _Float16* d = buf + wid * 512;
    gload_lds16(g,          d);
    gload_lds16(g + 16384,  d + 2048);
    gload_lds16(g + 32768,  d + 4096);
    gload_lds16(g + 49152,  d + 6144);
  };
  auto stage_v = [&](int kt, _Float16* buf){
    const _Float16* g = gVs + (size_t)kt * 64;
    _Float16* d = buf + wid * 512;
    gload_lds16(g,          d);
    gload_lds16(g + 65536,  d + 2048);
    gload_lds16(g + 131072, d + 4096);
    gload_lds16(g + 196608, d + 6144);
  };

  // ---- pass 1: exact row max + denominator (K dbuf, 1 barrier/iter) ----
  stage_k(0, sKV[0]);
  __syncthreads();                              // vmcnt drained -> tile 0 ready

  for (int kt = 0; kt <= qb; ++kt){
    if (kt < qb) stage_k(kt + 1, sKV[(kt + 1) & 1]);   // flies under MFMA+softmax
    const _Float16* kb = sKV[kt & 1];
    float sv[4][4];
    const bool diag = (kt == qb);               // wave-uniform
    __builtin_amdgcn_s_setprio(1);
#pragma unroll
    for (int nt = 0; nt < 4; nt++){
      floatx4 c = {};
#pragma unroll
      for (int kk = 0; kk < 4; kk++){
        half8 bf = *(const half8*)(kb + nt * 2048 + krd[kk]);
        c = __builtin_amdgcn_mfma_f32_16x16x32_f16(qf[kk], bf, c, 0, 0, 0);
      }
      if (diag){
        int kpos = kt * 64 + nt * 16 + l16;
#pragma unroll
        for (int rr = 0; rr < 4; rr++)
          sv[nt][rr] = (kpos <= q_of_reg + rr) ? c[rr] * qkscale : -__builtin_inff();
      } else {
#pragma unroll
        for (int rr = 0; rr < 4; rr++) sv[nt][rr] = c[rr] * qkscale;
      }
    }
    __builtin_amdgcn_s_setprio(0);
#pragma unroll
    for (int rr = 0; rr < 4; rr++){
      float lmax = fmaxf(fmaxf(sv[0][rr], sv[1][rr]), fmaxf(sv[2][rr], sv[3][rr]));
      float tmax = grp16_max(lmax);
      float mnew = fmaxf(mrow[rr], tmax);
      float lsum = 0.f;
#pragma unroll
      for (int nt = 0; nt < 4; nt++) lsum += __expf(sv[nt][rr] - mnew);
      lsum = grp16_sum(lsum);
      lrow[rr] = lrow[rr] * __expf(mrow[rr] - mnew) + lsum;
      mrow[rr] = mnew;
    }
    __syncthreads();                            // drains vmcnt -> next tile ready
  }

  float il[4];   // 127 / l  (rcp: ~1ulp, quant boundary noise only)
#pragma unroll
  for (int rr = 0; rr < 4; rr++) il[rr] = QMAXF * __builtin_amdgcn_rcpf(lrow[rr]);

  // ---- pass 2: recompute, quantize probs, PV ----
  floatx4 accO[8] = {};
  _Float16* sKb = sKV[0];
  _Float16* sVb = sKV[1];
  _Float16* sPw = sP[wid];

  for (int kt = 0; kt <= qb; ++kt){
    __syncthreads();                            // all waves done reading sKb/sVb
    stage_k(kt, sKb);
    stage_v(kt, sVb);
    __syncthreads();                            // vmcnt drained -> tile ready
    const bool diag = (kt == qb);
    __builtin_amdgcn_s_setprio(1);
#pragma unroll
    for (int nt = 0; nt < 4; nt++){
      floatx4 c = {};
#pragma unroll
      for (int kk = 0; kk < 4; kk++){
        half8 bf = *(const half8*)(sKb + nt * 2048 + krd[kk]);
        c = __builtin_amdgcn_mfma_f32_16x16x32_f16(qf[kk], bf, c, 0, 0, 0);
      }
      int kpos = kt * 64 + nt * 16 + l16;
#pragma unroll
      for (int rr = 0; rr < 4; rr++){
        float pq = fminf(rintf(__expf(c[rr] * qkscale - mrow[rr]) * il[rr]), 127.f);
        if (diag && kpos > q_of_reg + rr) pq = 0.f;
        int row = quad * 4 + rr;
        sPw[row * 64 + ((nt * 2 + (l16 >> 3)) ^ (row & 7)) * 8 + (l16 & 7)] = (_Float16)pq;
      }
    }
    __builtin_amdgcn_s_setprio(0);
    // sP is wave-private: intra-wave lgkmcnt ordering, no barrier needed
    half8 pf0 = *(const half8*)(sPw + vrd0);    // P read, same swizzle form as V
    half8 pf1 = *(const half8*)(sPw + vrd1);
    __builtin_amdgcn_s_setprio(1);
#pragma unroll
    for (int dt = 0; dt < 8; dt++){
      half8 b0 = *(const half8*)(sVb + dt * 1024 + vrd0);
      half8 b1 = *(const half8*)(sVb + dt * 1024 + vrd1);
      accO[dt] = __builtin_amdgcn_mfma_f32_16x16x32_f16(pf0, b0, accO[dt], 0, 0, 0);
      accO[dt] = __builtin_amdgcn_mfma_f32_16x16x32_f16(pf1, b1, accO[dt], 0, 0, 0);
    }
    __builtin_amdgcn_s_setprio(0);
  }

#pragma unroll
  for (int dt = 0; dt < 8; dt++){
    int col = h * 128 + dt * 16 + l16;
#pragma unroll
    for (int rr = 0; rr < 4; rr++)
      AO[(size_t)(q_of_reg + rr) * 4096 + col] = accO[dt][rr] * osc;
  }
}

// ---------------- launch ----------------
extern "C" void kernel_launch(void* const* d_in, const int* in_sizes, int n_in,
                              void* d_out, int out_size, void* d_ws, size_t ws_size,
                              hipStream_t stream)
{
  const float* hidden = (const float*)d_in[0];
  // d_in[1] attention_mask: deterministic causal -> computed analytically
  const float* cosb = (const float*)d_in[2];
  const float* sinb = (const float*)d_in[3];
  const float* wq = (const float*)d_in[4];
  const float* wk = (const float*)d_in[5];
  const float* wv = (const float*)d_in[6];
  const float* wo = (const float*)d_in[7];
  float* out = (float*)d_out;

  char* ws = (char*)d_ws;
  size_t off = 0;
  auto alloc = [&](size_t bytes){ size_t o = off; off += (bytes + 255) & ~(size_t)255; return o; };
  float*    scal  = (float*)   (ws + alloc(64));                       // amax: x,q,k,v,ao
  float*    wsc   = (float*)   (ws + alloc(10240 * 4));                // per-row weight scales
  float*    qpart = (float*)   (ws + alloc(ROPE_BLOCKS * 4));
  float*    kpart = (float*)   (ws + alloc(ROPE_BLOCKS * 4));
  _Float16* Wall  = (_Float16*)(ws + alloc((size_t)6144 * 4096 * 2));  // wq|wk|wv int-f16
  _Float16* Wo    = (_Float16*)(ws + alloc((size_t)4096 * 4096 * 2));
  _Float16* Xq    = (_Float16*)(ws + alloc((size_t)2048 * 4096 * 2));
  float*    Y     = (float*)   (ws + alloc((size_t)2048 * 6144 * 4));  // qkv proj fp32
  // aliases (lifetimes disjoint): total ws ~151 MB
  _Float16* Qh  = Xq;                                   // written after GEMM1 read of Xq
  _Float16* Kh  = Wall;                                 // written after GEMM1 read of Wall
  _Float16* Vt  = Wall + (size_t)2048 * 1024;
  float*    AO  = Y;                                    // written after Y consumed
  _Float16* AOq = (_Float16*)((char*)Y + (size_t)2048 * 4096 * 4);

  unsigned* su = (unsigned*)scal;

  k_init<<<dim3(1), dim3(64), 0, stream>>>(scal);
  k_quant_w<<<dim3(10240), dim3(256), 0, stream>>>(wq, wk, wv, wo, Wall, Wo, wsc);
  k_amax<<<dim3(256), dim3(256), 0, stream>>>(hidden, (size_t)(2048 * 4096 / 4), su + 0);
  k_quant<<<dim3(2048), dim3(256), 0, stream>>>(hidden, Xq, (size_t)(2048 * 4096 / 4), scal + 0);
  k_gemm_nt<<<dim3(16, 48), dim3(256), 0, stream>>>(Xq, Wall, scal + 0, wsc, Y, 2048, 6144, 4096);
  k_rope<<<dim3(ROPE_BLOCKS), dim3(256), 0, stream>>>(Y, cosb, sinb, qpart, kpart);
  k_reduce_qk<<<dim3(2), dim3(256), 0, stream>>>(qpart, kpart, scal);
  k_amax_v<<<dim3(256), dim3(256), 0, stream>>>(Y, su + 3);
  k_quant_qk<<<dim3(10240), dim3(256), 0, stream>>>(Y, Qh, Kh, scal);
  k_quant_vt<<<dim3(32, 8, 2), dim3(256), 0, stream>>>(Y, Vt, scal);
  k_attn<<<dim3(32, 32), dim3(256), 0, stream>>>(Qh, Kh, Vt, scal, AO);
  k_amax<<<dim3(256), dim3(256), 0, stream>>>(AO, (size_t)(2048 * 4096 / 4), su + 4);
  k_quant<<<dim3(2048), dim3(256), 0, stream>>>(AO, AOq, (size_t)(2048 * 4096 / 4), scal + 4);
  k_gemm_nt<<<dim3(16, 32), dim3(256), 0, stream>>>(AOq, Wo, scal + 4, wsc + 6144, out, 2048, 4096, 4096);
}

// Round 5
// 651.788 us; speedup vs baseline: 1.1284x; 1.0431x over previous
//
#include <hip/hip_runtime.h>
#include <cstdint>
#include <cstddef>

// QuantLlamaAttention: int8 fake-quant Llama attention block, MI355X (gfx950).
// All matmuls carry quantized INTEGER values in _Float16 (exact for |v|<=2048)
// through mfma_f32_16x16x32_f16, fp32 accumulate, scales applied in epilogue.
// softmax prob amax is exactly 1.0 (causal row 0) -> static prob scale 1/127,
// enabling a two-pass flash attention with exact quantization (no S matrix).
//
// R1: block partials / 1 atomic per block (amax).
// R2: 368->147us: __expf, diag-only masking, q-pairing, gload_lds GEMM.
// R3/R4: launch_bounds(256,4) VGPR=64 spills -> 177us. 40KB LDS + swizzle kept.
// R5: gload_lds pre-swizzled K/V staging, spill fixed -> 143us, but MfmaUtil
//     still 15% / Occ 21%: occupancy moves are NOT the lever; the per-wave
//     serial chain (32 shfl softmax, sP LDS roundtrip, 2-3 barriers/tile) is.
// R6: SWAPPED-OPERAND rewrite (m214 pattern): mfma(K,Q) -> lane l16 owns one
//     full q-row of S; A/B frags of X and X^T have identical lane contents so
//     qf/kf loads are unchanged. Softmax row-reduce: 15 fmax + 2 shfl (was 32
//     shfl). P never touches LDS: cvt_pkrtz + shfl-pairs + selects build the
//     PV B-frag; PV also swapped (mfma(vfrag, pb, acc)), epilogue becomes
//     8 coalesced float4 stores. sP deleted -> K+V BOTH double-buffered (64KB,
//     free at grid-capped 2 blocks/CU), 1 barrier/tile in both passes, DMA one
//     tile ahead. Grid (16,32): uniform paired blocks {i,31-i} = 33 units.
// R7: resubmit of R6 (container flake, no counters); fragment-layout/exchange/
//     barrier/bounds re-derived clean.

#define S_LEN   2048
#define HDIM    4096
#define NHEADS  32
#define NKVH    8
#define HEADD   128
#define QMAXF   127.0f
#define ROPE_BLOCKS 20480

typedef _Float16 half8  __attribute__((ext_vector_type(8)));
typedef _Float16 half2v __attribute__((ext_vector_type(2)));
typedef float    floatx4 __attribute__((ext_vector_type(4)));

// ---------------- helpers ----------------
__device__ __forceinline__ float wave_max64(float v){
#pragma unroll
  for (int off = 32; off > 0; off >>= 1) v = fmaxf(v, __shfl_xor(v, off));
  return v;
}
// reduce across the 4 quad-lanes (l16, l16+16, l16+32, l16+48)
__device__ __forceinline__ float quad_max(float v){
  v = fmaxf(v, __shfl_xor(v, 16));
  v = fmaxf(v, __shfl_xor(v, 32));
  return v;
}
__device__ __forceinline__ float quad_sum(float v){
  v += __shfl_xor(v, 16);
  v += __shfl_xor(v, 32);
  return v;
}
__device__ __forceinline__ void atomic_max_f(unsigned* p, float v){
  atomicMax(p, __float_as_uint(v));   // v >= 0: uint bits order-preserving
}
__device__ __forceinline__ float q8(float x, float scale){
  return fminf(fmaxf(rintf(x / scale), -128.f), 127.f);  // rintf = half-even, matches jnp.round
}
// async global->LDS, 16B per lane. HW: LDS dest = wave-uniform base + lane*16.
__device__ __forceinline__ void gload_lds16(const _Float16* g, _Float16* l){
  __builtin_amdgcn_global_load_lds((const __attribute__((address_space(1))) void*)g,
                                   (__attribute__((address_space(3))) void*)l, 16, 0, 0);
}

// block-level max of per-wave maxima (256 threads = 4 waves), then ONE atomic
__device__ __forceinline__ void block_atomic_max(float m, unsigned* out){
  m = wave_max64(m);
  __shared__ float red[4];
  int wid = threadIdx.x >> 6;
  if ((threadIdx.x & 63) == 0) red[wid] = m;
  __syncthreads();
  if (threadIdx.x == 0)
    atomic_max_f(out, fmaxf(fmaxf(red[0], red[1]), fmaxf(red[2], red[3])));
}

// ---------------- tiny kernels ----------------
__global__ void k_init(float* scal){ if (threadIdx.x < 16) scal[threadIdx.x] = 0.0f; }

__global__ void k_amax(const float* __restrict__ x, size_t n4, unsigned* __restrict__ out){
  size_t i = (size_t)blockIdx.x * blockDim.x + threadIdx.x;
  size_t stride = (size_t)gridDim.x * blockDim.x;
  float m = 0.f;
  for (; i < n4; i += stride){
    float4 v = ((const float4*)x)[i];
    m = fmaxf(m, fmaxf(fmaxf(fabsf(v.x), fabsf(v.y)), fmaxf(fabsf(v.z), fabsf(v.w))));
  }
  block_atomic_max(m, out);
}

// amax over the V slice (cols [5120,6144)) of Y[2048][6144]
__global__ void k_amax_v(const float* __restrict__ Y, unsigned* __restrict__ out){
  size_t i = (size_t)blockIdx.x * blockDim.x + threadIdx.x;
  size_t stride = (size_t)gridDim.x * blockDim.x;
  float m = 0.f;
  for (size_t e = i; e < (size_t)S_LEN * 1024; e += stride){
    size_t s = e >> 10; int c = (int)(e & 1023);
    m = fmaxf(m, fabsf(Y[s * 6144 + 5120 + c]));
  }
  block_atomic_max(m, out);
}

// per-tensor quantize fp32 -> integer-valued f16
__global__ void k_quant(const float* __restrict__ x, _Float16* __restrict__ q,
                        size_t n4, const float* __restrict__ amax){
  float scale = fmaxf(*amax, 1e-8f) / QMAXF;
  size_t i = (size_t)blockIdx.x * blockDim.x + threadIdx.x;
  size_t stride = (size_t)gridDim.x * blockDim.x;
  for (; i < n4; i += stride){
    float4 v = ((const float4*)x)[i];
    union { _Float16 h[4]; uint2 u; } pk;
    pk.h[0] = (_Float16)q8(v.x, scale);
    pk.h[1] = (_Float16)q8(v.y, scale);
    pk.h[2] = (_Float16)q8(v.z, scale);
    pk.h[3] = (_Float16)q8(v.w, scale);
    ((uint2*)q)[i] = pk.u;
  }
}

// per-row weight quantization: rows 0..6143 -> Wall (wq|wk|wv), 6144..10239 -> Wo
__global__ __launch_bounds__(256) void k_quant_w(
    const float* __restrict__ wq, const float* __restrict__ wk,
    const float* __restrict__ wv, const float* __restrict__ wo,
    _Float16* __restrict__ Wall, _Float16* __restrict__ Wo,
    float* __restrict__ wsc)
{
  int row = blockIdx.x;
  const float* src; _Float16* dst;
  if (row < 4096)      { src = wq + (size_t)row * HDIM;          dst = Wall + (size_t)row * HDIM; }
  else if (row < 5120) { src = wk + (size_t)(row - 4096) * HDIM; dst = Wall + (size_t)row * HDIM; }
  else if (row < 6144) { src = wv + (size_t)(row - 5120) * HDIM; dst = Wall + (size_t)row * HDIM; }
  else                 { src = wo + (size_t)(row - 6144) * HDIM; dst = Wo + (size_t)(row - 6144) * HDIM; }
  float4 v[4]; float m = 0.f;
#pragma unroll
  for (int i = 0; i < 4; i++){
    v[i] = ((const float4*)src)[threadIdx.x + i * 256];
    m = fmaxf(m, fmaxf(fmaxf(fabsf(v[i].x), fabsf(v[i].y)), fmaxf(fabsf(v[i].z), fabsf(v[i].w))));
  }
  m = wave_max64(m);
  __shared__ float red[4];
  int wid = threadIdx.x >> 6;
  if ((threadIdx.x & 63) == 0) red[wid] = m;
  __syncthreads();
  float am = fmaxf(fmaxf(red[0], red[1]), fmaxf(red[2], red[3]));
  float scale = fmaxf(am, 1e-8f) / QMAXF;
  if (threadIdx.x == 0) wsc[row] = scale;
#pragma unroll
  for (int i = 0; i < 4; i++){
    union { _Float16 h[4]; uint2 u; } pk;
    pk.h[0] = (_Float16)q8(v[i].x, scale);
    pk.h[1] = (_Float16)q8(v[i].y, scale);
    pk.h[2] = (_Float16)q8(v[i].z, scale);
    pk.h[3] = (_Float16)q8(v[i].w, scale);
    ((uint2*)dst)[threadIdx.x + i * 256] = pk.u;
  }
}

// RoPE in-place on Y (q: heads 0..31, k: heads 32..39) + per-block partials
__global__ __launch_bounds__(256) void k_rope(
    float* __restrict__ Y, const float* __restrict__ cosb,
    const float* __restrict__ sinb,
    float* __restrict__ qpart, float* __restrict__ kpart)
{
  int idx = blockIdx.x * 256 + threadIdx.x;   // 2048*40*64 total
  int s = idx / (40 * 64);
  int rem = idx - s * 40 * 64;
  int head = rem >> 6;        // wave-uniform (64 threads per head slot)
  int d = rem & 63;
  size_t base = (size_t)s * 6144 + (head < 32 ? head * 128 : 4096 + (head - 32) * 128);
  float x1 = Y[base + d], x2 = Y[base + d + 64];
  float c1 = cosb[s * 128 + d],      s1 = sinb[s * 128 + d];
  float c2 = cosb[s * 128 + d + 64], s2 = sinb[s * 128 + d + 64];
  float o1 = x1 * c1 - x2 * s1;
  float o2 = x2 * c2 + x1 * s2;
  Y[base + d] = o1; Y[base + d + 64] = o2;
  float m = wave_max64(fmaxf(fabsf(o1), fabsf(o2)));
  __shared__ float wmax[4]; __shared__ int wisq[4];
  int wid = threadIdx.x >> 6;
  if ((threadIdx.x & 63) == 0){ wmax[wid] = m; wisq[wid] = (head < 32); }
  __syncthreads();
  if (threadIdx.x == 0){
    float qm = 0.f, km = 0.f;
#pragma unroll
    for (int w = 0; w < 4; w++){
      if (wisq[w]) qm = fmaxf(qm, wmax[w]); else km = fmaxf(km, wmax[w]);
    }
    qpart[blockIdx.x] = qm; kpart[blockIdx.x] = km;
  }
}

// reduce rope partials: block 0 -> scal[1] (q), block 1 -> scal[2] (k)
__global__ __launch_bounds__(256) void k_reduce_qk(
    const float* __restrict__ qpart, const float* __restrict__ kpart,
    float* __restrict__ scal)
{
  const float* src = blockIdx.x ? kpart : qpart;
  float m = 0.f;
  for (int i = threadIdx.x; i < ROPE_BLOCKS; i += 256) m = fmaxf(m, src[i]);
  m = wave_max64(m);
  __shared__ float red[4];
  int wid = threadIdx.x >> 6;
  if ((threadIdx.x & 63) == 0) red[wid] = m;
  __syncthreads();
  if (threadIdx.x == 0)
    scal[1 + blockIdx.x] = fmaxf(fmaxf(red[0], red[1]), fmaxf(red[2], red[3]));
}

// quantize Q,K slices of Y (cols [0,5120)) -> Qh[2048][4096], Kh[2048][1024]
__global__ __launch_bounds__(256) void k_quant_qk(
    const float* __restrict__ Y, _Float16* __restrict__ Qh,
    _Float16* __restrict__ Kh, const float* __restrict__ scal)
{
  int i = blockIdx.x * 256 + threadIdx.x;       // 2048*5120/4 float4 units
  int s = i / 1280, c4 = i - s * 1280;
  int col = c4 * 4;
  float4 v = *(const float4*)(Y + (size_t)s * 6144 + col);
  float scale = fmaxf(col < 4096 ? scal[1] : scal[2], 1e-8f) / QMAXF;
  union { _Float16 h[4]; uint2 u; } pk;
  pk.h[0] = (_Float16)q8(v.x, scale);
  pk.h[1] = (_Float16)q8(v.y, scale);
  pk.h[2] = (_Float16)q8(v.z, scale);
  pk.h[3] = (_Float16)q8(v.w, scale);
  if (col < 4096) *(uint2*)(Qh + (size_t)s * 4096 + col) = pk.u;
  else            *(uint2*)(Kh + (size_t)s * 1024 + (col - 4096)) = pk.u;
}

// quantize V slice of Y with LDS-tiled transpose -> Vt[8][128][2048]
// block: 64 s x 64 d; grid (32 s-tiles, 8 kvh, 2 d-halves)
__global__ __launch_bounds__(256) void k_quant_vt(
    const float* __restrict__ Y, _Float16* __restrict__ Vt,
    const float* __restrict__ scal)
{
  __shared__ _Float16 sT[64][72];      // [d][s], stride 144 B (16B-aligned rows)
  const int s0 = blockIdx.x * 64, kvh = blockIdx.y, dh = blockIdx.z;
  const float scale = fmaxf(scal[3], 1e-8f) / QMAXF;
  const int d = threadIdx.x & 63, srow = threadIdx.x >> 6;
#pragma unroll
  for (int i = 0; i < 16; i++){
    int s = srow + i * 4;
    float v = Y[(size_t)(s0 + s) * 6144 + 5120 + kvh * 128 + dh * 64 + d];
    sT[d][s] = (_Float16)q8(v, scale);
  }
  __syncthreads();
  const int dr = threadIdx.x >> 2, j = threadIdx.x & 3;   // 64 d-rows x 4 lanes
  _Float16* dst = Vt + (size_t)kvh * HEADD * S_LEN + (size_t)(dh * 64 + dr) * S_LEN + s0 + j * 16;
  *(uint4*)(dst)     = *(const uint4*)(&sT[dr][j * 16]);
  *(uint4*)(dst + 8) = *(const uint4*)(&sT[dr][j * 16 + 8]);
}

// ---------------- GEMM: C[M][N] = (A[M][K] . B[N][K]^T) * sa * sb[n] ----------------
// m97 structure: unpadded [128][32] LDS, global_load_lds width=16, 2 barriers/iter
__global__ __launch_bounds__(256) void k_gemm_nt(
    const _Float16* __restrict__ A, const _Float16* __restrict__ B,
    const float* __restrict__ amax_a, const float* __restrict__ sb,
    float* __restrict__ C, int M, int N, int K)
{
  __shared__ _Float16 sA[128 * 32];
  __shared__ _Float16 sB[128 * 32];
  const int m0 = blockIdx.x * 128;
  const int n0 = blockIdx.y * 128;
  const int tid = threadIdx.x;
  const int w = tid >> 6, lane = tid & 63;
  const int quad = lane >> 4, l16 = lane & 15;
  const int wm = (w & 1) * 64, wn = (w >> 1) * 64;
  floatx4 acc[4][4] = {};
  const int srow = w * 16 + (lane >> 2);
  const int scol = (lane & 3) * 8;
  const _Float16* gA0 = A + (size_t)(m0 + srow) * K + scol;
  const _Float16* gA1 = A + (size_t)(m0 + 64 + srow) * K + scol;
  const _Float16* gB0 = B + (size_t)(n0 + srow) * K + scol;
  const _Float16* gB1 = B + (size_t)(n0 + 64 + srow) * K + scol;
  _Float16* dA0 = sA + w * 512 + lane * 8;
  _Float16* dA1 = sA + 2048 + w * 512 + lane * 8;
  _Float16* dB0 = sB + w * 512 + lane * 8;
  _Float16* dB1 = sB + 2048 + w * 512 + lane * 8;

  for (int k0 = 0; k0 < K; k0 += 32){
    __syncthreads();                       // prev iter's LDS reads done
    gload_lds16(gA0 + k0, dA0);
    gload_lds16(gA1 + k0, dA1);
    gload_lds16(gB0 + k0, dB0);
    gload_lds16(gB1 + k0, dB1);
    __syncthreads();                       // drains vmcnt before barrier
    half8 af[4], bf[4];
#pragma unroll
    for (int i = 0; i < 4; i++){
      af[i] = *(const half8*)(sA + (wm + i * 16 + l16) * 32 + quad * 8);
      bf[i] = *(const half8*)(sB + (wn + i * 16 + l16) * 32 + quad * 8);
    }
#pragma unroll
    for (int i = 0; i < 4; i++)
#pragma unroll
      for (int j = 0; j < 4; j++)
        acc[i][j] = __builtin_amdgcn_mfma_f32_16x16x32_f16(af[i], bf[j], acc[i][j], 0, 0, 0);
  }
  const float sa = fmaxf(*amax_a, 1e-8f) / QMAXF;
#pragma unroll
  for (int i = 0; i < 4; i++){
    int row = m0 + wm + i * 16 + quad * 4;
#pragma unroll
    for (int j = 0; j < 4; j++){
      int col = n0 + wn + j * 16 + l16;
      float sc2 = sa * sb[col];
#pragma unroll
      for (int rr = 0; rr < 4; rr++)
        C[(size_t)(row + rr) * N + col] = acc[i][j][rr] * sc2;
    }
  }
}

// ---------------- flash attention, swapped-operand, exact quantized softmax ----------------
// grid (16,32): uniform paired blocks, qb in {pair, 31-pair}, 33 tiles/pass.
// Swapped QK: c = mfma(kf, qf) -> lane l16 = q-row, reg (nt,quad,rr) = k.
// P stays in registers; PV B-frag built via cvt_pkrtz + shfl; PV swapped:
// accO = mfma(vfrag, pb) -> lane l16 = q-row, reg = d -> float4 epilogue.
// LDS 64KB: K,V both double-buffered, 1 barrier/tile both passes, DMA 1 ahead.
// 16B-chunk XOR swizzle on K/V (pre-swizzled gload source; involution on read).
__global__ __launch_bounds__(256, 2) void k_attn(
    const _Float16* __restrict__ Qh,  // [2048][4096]  (s, h*128+d) int-f16
    const _Float16* __restrict__ Kh,  // [2048][1024]  (s, kvh*128+d)
    const _Float16* __restrict__ Vt,  // [8][128][2048] (kvh, d, s)
    const float* __restrict__ scal,
    float* __restrict__ AO)           // [2048][4096] fp32
{
  const int pair = blockIdx.x;   // 0..15
  const int h    = blockIdx.y;   // 0..31
  const int kvh  = h >> 2;       // GQA groups=4
  const int tid  = threadIdx.x;
  const int wid  = tid >> 6, lane = tid & 63;
  const int quad = lane >> 4, l16 = lane & 15;

  __shared__ _Float16 sK[2][8192];    // K tile [64 k][128 d], dbuf
  __shared__ _Float16 sV[2][8192];    // V tile [128 d][64 k], dbuf

  const float s_q = fmaxf(scal[1], 1e-8f) / QMAXF;
  const float s_k = fmaxf(scal[2], 1e-8f) / QMAXF;
  const float s_v = fmaxf(scal[3], 1e-8f) / QMAXF;
  const float qkscale = s_q * s_k * 0.08838834764831845f;  // * HD^-0.5
  const float osc = s_v * (1.0f / QMAXF);

  // ---- staging addresses (pre-swizzled global source, linear LDS dest) ----
  const int srow7 = (wid * 4 + quad) & 7;
  const int sch   = (l16 & 8) | ((l16 ^ srow7) & 7);
  const _Float16* gKs = Kh + (size_t)(wid * 4 + quad) * 1024 + (size_t)kvh * 128 + sch * 8;
  const int vrg = lane >> 3, vp = lane & 7;
  const _Float16* gVs = Vt + (size_t)kvh * (HEADD * S_LEN)
                           + (size_t)(wid * 8 + vrg) * S_LEN + ((vp ^ vrg) & 7) * 8;

  // ---- swizzled read offsets ----
  int krd[4];                                   // K read: row = nt*16+l16 (row&7 == l16&7)
#pragma unroll
  for (int kk = 0; kk < 4; kk++){
    int c = kk * 4 + quad;
    krd[kk] = l16 * 128 + ((c & 8) | ((c ^ (l16 & 7)) & 7)) * 8;
  }
  const int vrd0 = l16 * 64 + ((quad       ^ (l16 & 7)) & 7) * 8;  // V read, k 0..31
  const int vrd1 = l16 * 64 + (((quad ^ 4) ^ (l16 & 7)) & 7) * 8;  // V read, k 32..63

  // P-exchange source lanes: target word w needs lane quad' = 2*(quad&1) + (w>>1)
  const int sl0 = l16 + 32 * (quad & 1);    // w = 0,1
  const int sl1 = sl0 + 16;                 // w = 2,3

  auto stage_k = [&](int kt, int buf){
    const _Float16* g = gKs + (size_t)kt * 65536;
    _Float16* d = sK[buf] + wid * 512;
    gload_lds16(g,          d);
    gload_lds16(g + 16384,  d + 2048);
    gload_lds16(g + 32768,  d + 4096);
    gload_lds16(g + 49152,  d + 6144);
  };
  auto stage_v = [&](int kt, int buf){
    const _Float16* g = gVs + (size_t)kt * 64;
    _Float16* d = sV[buf] + wid * 512;
    gload_lds16(g,          d);
    gload_lds16(g + 65536,  d + 2048);
    gload_lds16(g + 131072, d + 4096);
    gload_lds16(g + 196608, d + 6144);
  };

  for (int half = 0; half < 2; half++){
    const int qb = half ? (31 - pair) : pair;
    const int ql = qb * 64 + wid * 16 + l16;     // this lane's q-row (swapped layout)
    half8 qf[4];
#pragma unroll
    for (int kk = 0; kk < 4; kk++)
      qf[kk] = *(const half8*)(Qh + (size_t)ql * 4096 + h * 128 + kk * 32 + quad * 8);

    float m = -__builtin_inff(), l = 0.f;

    // ---- pass 1: exact row max + denominator ----
    stage_k(0, 0);
    __syncthreads();
    for (int kt = 0; kt <= qb; ++kt){
      if (kt < qb) stage_k(kt + 1, (kt + 1) & 1);
      const _Float16* kb = sK[kt & 1];
      const bool diag = (kt == qb);
      float s[4][4];
      __builtin_amdgcn_s_setprio(1);
#pragma unroll
      for (int nt = 0; nt < 4; nt++){
        floatx4 c = {};
#pragma unroll
        for (int kk = 0; kk < 4; kk++){
          half8 kf = *(const half8*)(kb + nt * 2048 + krd[kk]);
          c = __builtin_amdgcn_mfma_f32_16x16x32_f16(kf, qf[kk], c, 0, 0, 0);
        }
#pragma unroll
        for (int rr = 0; rr < 4; rr++){
          int kpos = kt * 64 + nt * 16 + quad * 4 + rr;
          float v = c[rr] * qkscale;
          s[nt][rr] = (diag && kpos > ql) ? -__builtin_inff() : v;
        }
      }
      __builtin_amdgcn_s_setprio(0);
      float tm = s[0][0];
#pragma unroll
      for (int nt = 0; nt < 4; nt++)
#pragma unroll
        for (int rr = 0; rr < 4; rr++) tm = fmaxf(tm, s[nt][rr]);
      tm = quad_max(tm);
      float mnew = fmaxf(m, tm);
      float ls = 0.f;
#pragma unroll
      for (int nt = 0; nt < 4; nt++)
#pragma unroll
        for (int rr = 0; rr < 4; rr++) ls += __expf(s[nt][rr] - mnew);
      ls = quad_sum(ls);
      l = l * __expf(m - mnew) + ls;
      m = mnew;
      __syncthreads();                           // drains vmcnt -> next tile ready
    }
    const float il = QMAXF * __builtin_amdgcn_rcpf(l);

    // ---- pass 2: recompute, quantize probs in-register, PV ----
    floatx4 accO[8] = {};
    stage_k(0, 0); stage_v(0, 0);
    __syncthreads();
    for (int kt = 0; kt <= qb; ++kt){
      if (kt < qb){ stage_k(kt + 1, (kt + 1) & 1); stage_v(kt + 1, (kt + 1) & 1); }
      const _Float16* kb = sK[kt & 1];
      const _Float16* vb = sV[kt & 1];
      const bool diag = (kt == qb);
      float p[4][4];
      __builtin_amdgcn_s_setprio(1);
#pragma unroll
      for (int nt = 0; nt < 4; nt++){
        floatx4 c = {};
#pragma unroll
        for (int kk = 0; kk < 4; kk++){
          half8 kf = *(const half8*)(kb + nt * 2048 + krd[kk]);
          c = __builtin_amdgcn_mfma_f32_16x16x32_f16(kf, qf[kk], c, 0, 0, 0);
        }
#pragma unroll
        for (int rr = 0; rr < 4; rr++) p[nt][rr] = c[rr];
      }
      __builtin_amdgcn_s_setprio(0);
      // quantize: pq = min(rint(exp(s - m) * 127/l), 127), 0 beyond diagonal
      unsigned ph[4][2];
#pragma unroll
      for (int nt = 0; nt < 4; nt++){
        float pq[4];
#pragma unroll
        for (int rr = 0; rr < 4; rr++){
          int kpos = kt * 64 + nt * 16 + quad * 4 + rr;
          float v = fminf(rintf(__expf(p[nt][rr] * qkscale - m) * il), 127.f);
          pq[rr] = (diag && kpos > ql) ? 0.f : v;
        }
        ph[nt][0] = __builtin_bit_cast(unsigned, __builtin_amdgcn_cvt_pkrtz(pq[0], pq[1]));
        ph[nt][1] = __builtin_bit_cast(unsigned, __builtin_amdgcn_cvt_pkrtz(pq[2], pq[3]));
      }
      // exchange: build PV B-frags pb[ks]: word w <- lane quad'=2*(quad&1)+(w>>1),
      // reg ph[2ks + (quad>>1)][w&1]
      half8 pb[2];
      const bool hi = (quad >= 2);
#pragma unroll
      for (int ks = 0; ks < 2; ks++){
        unsigned wa0 = __shfl((int)ph[2 * ks][0],     sl0);
        unsigned wb0 = __shfl((int)ph[2 * ks + 1][0], sl0);
        unsigned wa1 = __shfl((int)ph[2 * ks][1],     sl0);
        unsigned wb1 = __shfl((int)ph[2 * ks + 1][1], sl0);
        unsigned wa2 = __shfl((int)ph[2 * ks][0],     sl1);
        unsigned wb2 = __shfl((int)ph[2 * ks + 1][0], sl1);
        unsigned wa3 = __shfl((int)ph[2 * ks][1],     sl1);
        unsigned wb3 = __shfl((int)ph[2 * ks + 1][1], sl1);
        union { unsigned w[4]; half8 v; } u;
        u.w[0] = hi ? wb0 : wa0;
        u.w[1] = hi ? wb1 : wa1;
        u.w[2] = hi ? wb2 : wa2;
        u.w[3] = hi ? wb3 : wa3;
        pb[ks] = u.v;
      }
      __builtin_amdgcn_s_setprio(1);
#pragma unroll
      for (int dt = 0; dt < 8; dt++){
        half8 v0 = *(const half8*)(vb + dt * 1024 + vrd0);
        half8 v1 = *(const half8*)(vb + dt * 1024 + vrd1);
        accO[dt] = __builtin_amdgcn_mfma_f32_16x16x32_f16(v0, pb[0], accO[dt], 0, 0, 0);
        accO[dt] = __builtin_amdgcn_mfma_f32_16x16x32_f16(v1, pb[1], accO[dt], 0, 0, 0);
      }
      __builtin_amdgcn_s_setprio(0);
      __syncthreads();                           // drains vmcnt -> next tile ready
    }

    // epilogue: lane l16 = q-row, reg (dt,quad,rr) = d -> coalesced float4
#pragma unroll
    for (int dt = 0; dt < 8; dt++){
      float4 o;
      o.x = accO[dt][0] * osc; o.y = accO[dt][1] * osc;
      o.z = accO[dt][2] * osc; o.w = accO[dt][3] * osc;
      *(float4*)(AO + (size_t)ql * 4096 + h * 128 + dt * 16 + quad * 4) = o;
    }
  }
}

// ---------------- launch ----------------
extern "C" void kernel_launch(void* const* d_in, const int* in_sizes, int n_in,
                              void* d_out, int out_size, void* d_ws, size_t ws_size,
                              hipStream_t stream)
{
  const float* hidden = (const float*)d_in[0];
  // d_in[1] attention_mask: deterministic causal -> computed analytically
  const float* cosb = (const float*)d_in[2];
  const float* sinb = (const float*)d_in[3];
  const float* wq = (const float*)d_in[4];
  const float* wk = (const float*)d_in[5];
  const float* wv = (const float*)d_in[6];
  const float* wo = (const float*)d_in[7];
  float* out = (float*)d_out;

  char* ws = (char*)d_ws;
  size_t off = 0;
  auto alloc = [&](size_t bytes){ size_t o = off; off += (bytes + 255) & ~(size_t)255; return o; };
  float*    scal  = (float*)   (ws + alloc(64));                       // amax: x,q,k,v,ao
  float*    wsc   = (float*)   (ws + alloc(10240 * 4));                // per-row weight scales
  float*    qpart = (float*)   (ws + alloc(ROPE_BLOCKS * 4));
  float*    kpart = (float*)   (ws + alloc(ROPE_BLOCKS * 4));
  _Float16* Wall  = (_Float16*)(ws + alloc((size_t)6144 * 4096 * 2));  // wq|wk|wv int-f16
  _Float16* Wo    = (_Float16*)(ws + alloc((size_t)4096 * 4096 * 2));
  _Float16* Xq    = (_Float16*)(ws + alloc((size_t)2048 * 4096 * 2));
  float*    Y     = (float*)   (ws + alloc((size_t)2048 * 6144 * 4));  // qkv proj fp32
  // aliases (lifetimes disjoint): total ws ~151 MB
  _Float16* Qh  = Xq;                                   // written after GEMM1 read of Xq
  _Float16* Kh  = Wall;                                 // written after GEMM1 read of Wall
  _Float16* Vt  = Wall + (size_t)2048 * 1024;
  float*    AO  = Y;                                    // written after Y consumed
  _Float16* AOq = (_Float16*)((char*)Y + (size_t)2048 * 4096 * 4);

  unsigned* su = (unsigned*)scal;

  k_init<<<dim3(1), dim3(64), 0, stream>>>(scal);
  k_quant_w<<<dim3(10240), dim3(256), 0, stream>>>(wq, wk, wv, wo, Wall, Wo, wsc);
  k_amax<<<dim3(256), dim3(256), 0, stream>>>(hidden, (size_t)(2048 * 4096 / 4), su + 0);
  k_quant<<<dim3(2048), dim3(256), 0, stream>>>(hidden, Xq, (size_t)(2048 * 4096 / 4), scal + 0);
  k_gemm_nt<<<dim3(16, 48), dim3(256), 0, stream>>>(Xq, Wall, scal + 0, wsc, Y, 2048, 6144, 4096);
  k_rope<<<dim3(ROPE_BLOCKS), dim3(256), 0, stream>>>(Y, cosb, sinb, qpart, kpart);
  k_reduce_qk<<<dim3(2), dim3(256), 0, stream>>>(qpart, kpart, scal);
  k_amax_v<<<dim3(256), dim3(256), 0, stream>>>(Y, su + 3);
  k_quant_qk<<<dim3(10240), dim3(256), 0, stream>>>(Y, Qh, Kh, scal);
  k_quant_vt<<<dim3(32, 8, 2), dim3(256), 0, stream>>>(Y, Vt, scal);
  k_attn<<<dim3(16, 32), dim3(256), 0, stream>>>(Qh, Kh, Vt, scal, AO);
  k_amax<<<dim3(256), dim3(256), 0, stream>>>(AO, (size_t)(2048 * 4096 / 4), su + 4);
  k_quant<<<dim3(2048), dim3(256), 0, stream>>>(AO, AOq, (size_t)(2048 * 4096 / 4), scal + 4);
  k_gemm_nt<<<dim3(16, 32), dim3(256), 0, stream>>>(AOq, Wo, scal + 4, wsc + 6144, out, 2048, 4096, 4096);
}

// Round 6
// 644.140 us; speedup vs baseline: 1.1418x; 1.0119x over previous
//
#include <hip/hip_runtime.h>
#include <cstdint>
#include <cstddef>

// QuantLlamaAttention: int8 fake-quant Llama attention block, MI355X (gfx950).
// All matmuls carry quantized INTEGER values in _Float16 (exact for |v|<=2048)
// through mfma_f32_16x16x32_f16, fp32 accumulate, scales applied in epilogue.
// softmax prob amax is exactly 1.0 (causal row 0) -> static prob scale 1/127,
// enabling a two-pass flash attention with exact quantization (no S matrix).
//
// R1: block partials / 1 atomic per block (amax).
// R2: 368->147us attn: __expf, diag masking, q-pairing, gload_lds GEMM.
// R3/R4: launch_bounds(256,4) VGPR cap spills -> regression; reverted.
// R5: gload_lds pre-swizzled K/V staging; occupancy not the lever.
// R6: swapped-operand attn (mfma(K,Q)): lane owns q-row, P in-register via
//     cvt_pkrtz+shfl, PV swapped, 1 barrier/tile. attn off the top-5.
// R8: GEMM is now the top (143us, MfmaUtil 31%, BANK_CONFLICT 1.3e7):
//     - BK=64 double-buffered counted-vmcnt pipeline: per tile
//       {reads+MFMA, barrier A, stage(t+2) into freed buf, vmcnt(8)
//       (t+1 landed, t+2 flies), barrier B} -> loads never exposed (T3/T4).
//     - 16B-chunk XOR swizzle on sA/sB (pre-swizzled gload source) ->
//       conflict-free ds_read_b128 (was 8-way).
//     - T1 bijective XCD swizzle on both GEMM grids (nwg%8==0) and attn
//       grid (each XCD owns one kvh -> K/V L2-resident).

#define S_LEN   2048
#define HDIM    4096
#define NHEADS  32
#define NKVH    8
#define HEADD   128
#define QMAXF   127.0f
#define ROPE_BLOCKS 20480

typedef _Float16 half8  __attribute__((ext_vector_type(8)));
typedef float    floatx4 __attribute__((ext_vector_type(4)));

// ---------------- helpers ----------------
__device__ __forceinline__ float wave_max64(float v){
#pragma unroll
  for (int off = 32; off > 0; off >>= 1) v = fmaxf(v, __shfl_xor(v, off));
  return v;
}
__device__ __forceinline__ float quad_max(float v){
  v = fmaxf(v, __shfl_xor(v, 16));
  v = fmaxf(v, __shfl_xor(v, 32));
  return v;
}
__device__ __forceinline__ float quad_sum(float v){
  v += __shfl_xor(v, 16);
  v += __shfl_xor(v, 32);
  return v;
}
__device__ __forceinline__ void atomic_max_f(unsigned* p, float v){
  atomicMax(p, __float_as_uint(v));   // v >= 0: uint bits order-preserving
}
__device__ __forceinline__ float q8(float x, float scale){
  return fminf(fmaxf(rintf(x / scale), -128.f), 127.f);  // rintf = half-even, matches jnp.round
}
// async global->LDS, 16B per lane. HW: LDS dest = wave-uniform base + lane*16.
__device__ __forceinline__ void gload_lds16(const _Float16* g, _Float16* l){
  __builtin_amdgcn_global_load_lds((const __attribute__((address_space(1))) void*)g,
                                   (__attribute__((address_space(3))) void*)l, 16, 0, 0);
}

// block-level max of per-wave maxima (256 threads = 4 waves), then ONE atomic
__device__ __forceinline__ void block_atomic_max(float m, unsigned* out){
  m = wave_max64(m);
  __shared__ float red[4];
  int wid = threadIdx.x >> 6;
  if ((threadIdx.x & 63) == 0) red[wid] = m;
  __syncthreads();
  if (threadIdx.x == 0)
    atomic_max_f(out, fmaxf(fmaxf(red[0], red[1]), fmaxf(red[2], red[3])));
}

// ---------------- tiny kernels ----------------
__global__ void k_init(float* scal){ if (threadIdx.x < 16) scal[threadIdx.x] = 0.0f; }

__global__ void k_amax(const float* __restrict__ x, size_t n4, unsigned* __restrict__ out){
  size_t i = (size_t)blockIdx.x * blockDim.x + threadIdx.x;
  size_t stride = (size_t)gridDim.x * blockDim.x;
  float m = 0.f;
  for (; i < n4; i += stride){
    float4 v = ((const float4*)x)[i];
    m = fmaxf(m, fmaxf(fmaxf(fabsf(v.x), fabsf(v.y)), fmaxf(fabsf(v.z), fabsf(v.w))));
  }
  block_atomic_max(m, out);
}

// amax over the V slice (cols [5120,6144)) of Y[2048][6144]
__global__ void k_amax_v(const float* __restrict__ Y, unsigned* __restrict__ out){
  size_t i = (size_t)blockIdx.x * blockDim.x + threadIdx.x;
  size_t stride = (size_t)gridDim.x * blockDim.x;
  float m = 0.f;
  for (size_t e = i; e < (size_t)S_LEN * 1024; e += stride){
    size_t s = e >> 10; int c = (int)(e & 1023);
    m = fmaxf(m, fabsf(Y[s * 6144 + 5120 + c]));
  }
  block_atomic_max(m, out);
}

// per-tensor quantize fp32 -> integer-valued f16
__global__ void k_quant(const float* __restrict__ x, _Float16* __restrict__ q,
                        size_t n4, const float* __restrict__ amax){
  float scale = fmaxf(*amax, 1e-8f) / QMAXF;
  size_t i = (size_t)blockIdx.x * blockDim.x + threadIdx.x;
  size_t stride = (size_t)gridDim.x * blockDim.x;
  for (; i < n4; i += stride){
    float4 v = ((const float4*)x)[i];
    union { _Float16 h[4]; uint2 u; } pk;
    pk.h[0] = (_Float16)q8(v.x, scale);
    pk.h[1] = (_Float16)q8(v.y, scale);
    pk.h[2] = (_Float16)q8(v.z, scale);
    pk.h[3] = (_Float16)q8(v.w, scale);
    ((uint2*)q)[i] = pk.u;
  }
}

// per-row weight quantization: rows 0..6143 -> Wall (wq|wk|wv), 6144..10239 -> Wo
__global__ __launch_bounds__(256) void k_quant_w(
    const float* __restrict__ wq, const float* __restrict__ wk,
    const float* __restrict__ wv, const float* __restrict__ wo,
    _Float16* __restrict__ Wall, _Float16* __restrict__ Wo,
    float* __restrict__ wsc)
{
  int row = blockIdx.x;
  const float* src; _Float16* dst;
  if (row < 4096)      { src = wq + (size_t)row * HDIM;          dst = Wall + (size_t)row * HDIM; }
  else if (row < 5120) { src = wk + (size_t)(row - 4096) * HDIM; dst = Wall + (size_t)row * HDIM; }
  else if (row < 6144) { src = wv + (size_t)(row - 5120) * HDIM; dst = Wall + (size_t)row * HDIM; }
  else                 { src = wo + (size_t)(row - 6144) * HDIM; dst = Wo + (size_t)(row - 6144) * HDIM; }
  float4 v[4]; float m = 0.f;
#pragma unroll
  for (int i = 0; i < 4; i++){
    v[i] = ((const float4*)src)[threadIdx.x + i * 256];
    m = fmaxf(m, fmaxf(fmaxf(fabsf(v[i].x), fabsf(v[i].y)), fmaxf(fabsf(v[i].z), fabsf(v[i].w))));
  }
  m = wave_max64(m);
  __shared__ float red[4];
  int wid = threadIdx.x >> 6;
  if ((threadIdx.x & 63) == 0) red[wid] = m;
  __syncthreads();
  float am = fmaxf(fmaxf(red[0], red[1]), fmaxf(red[2], red[3]));
  float scale = fmaxf(am, 1e-8f) / QMAXF;
  if (threadIdx.x == 0) wsc[row] = scale;
#pragma unroll
  for (int i = 0; i < 4; i++){
    union { _Float16 h[4]; uint2 u; } pk;
    pk.h[0] = (_Float16)q8(v[i].x, scale);
    pk.h[1] = (_Float16)q8(v[i].y, scale);
    pk.h[2] = (_Float16)q8(v[i].z, scale);
    pk.h[3] = (_Float16)q8(v[i].w, scale);
    ((uint2*)dst)[threadIdx.x + i * 256] = pk.u;
  }
}

// RoPE in-place on Y (q: heads 0..31, k: heads 32..39) + per-block partials
__global__ __launch_bounds__(256) void k_rope(
    float* __restrict__ Y, const float* __restrict__ cosb,
    const float* __restrict__ sinb,
    float* __restrict__ qpart, float* __restrict__ kpart)
{
  int idx = blockIdx.x * 256 + threadIdx.x;   // 2048*40*64 total
  int s = idx / (40 * 64);
  int rem = idx - s * 40 * 64;
  int head = rem >> 6;        // wave-uniform (64 threads per head slot)
  int d = rem & 63;
  size_t base = (size_t)s * 6144 + (head < 32 ? head * 128 : 4096 + (head - 32) * 128);
  float x1 = Y[base + d], x2 = Y[base + d + 64];
  float c1 = cosb[s * 128 + d],      s1 = sinb[s * 128 + d];
  float c2 = cosb[s * 128 + d + 64], s2 = sinb[s * 128 + d + 64];
  float o1 = x1 * c1 - x2 * s1;
  float o2 = x2 * c2 + x1 * s2;
  Y[base + d] = o1; Y[base + d + 64] = o2;
  float m = wave_max64(fmaxf(fabsf(o1), fabsf(o2)));
  __shared__ float wmax[4]; __shared__ int wisq[4];
  int wid = threadIdx.x >> 6;
  if ((threadIdx.x & 63) == 0){ wmax[wid] = m; wisq[wid] = (head < 32); }
  __syncthreads();
  if (threadIdx.x == 0){
    float qm = 0.f, km = 0.f;
#pragma unroll
    for (int w = 0; w < 4; w++){
      if (wisq[w]) qm = fmaxf(qm, wmax[w]); else km = fmaxf(km, wmax[w]);
    }
    qpart[blockIdx.x] = qm; kpart[blockIdx.x] = km;
  }
}

// reduce rope partials: block 0 -> scal[1] (q), block 1 -> scal[2] (k)
__global__ __launch_bounds__(256) void k_reduce_qk(
    const float* __restrict__ qpart, const float* __restrict__ kpart,
    float* __restrict__ scal)
{
  const float* src = blockIdx.x ? kpart : qpart;
  float m = 0.f;
  for (int i = threadIdx.x; i < ROPE_BLOCKS; i += 256) m = fmaxf(m, src[i]);
  m = wave_max64(m);
  __shared__ float red[4];
  int wid = threadIdx.x >> 6;
  if ((threadIdx.x & 63) == 0) red[wid] = m;
  __syncthreads();
  if (threadIdx.x == 0)
    scal[1 + blockIdx.x] = fmaxf(fmaxf(red[0], red[1]), fmaxf(red[2], red[3]));
}

// quantize Q,K slices of Y (cols [0,5120)) -> Qh[2048][4096], Kh[2048][1024]
__global__ __launch_bounds__(256) void k_quant_qk(
    const float* __restrict__ Y, _Float16* __restrict__ Qh,
    _Float16* __restrict__ Kh, const float* __restrict__ scal)
{
  int i = blockIdx.x * 256 + threadIdx.x;       // 2048*5120/4 float4 units
  int s = i / 1280, c4 = i - s * 1280;
  int col = c4 * 4;
  float4 v = *(const float4*)(Y + (size_t)s * 6144 + col);
  float scale = fmaxf(col < 4096 ? scal[1] : scal[2], 1e-8f) / QMAXF;
  union { _Float16 h[4]; uint2 u; } pk;
  pk.h[0] = (_Float16)q8(v.x, scale);
  pk.h[1] = (_Float16)q8(v.y, scale);
  pk.h[2] = (_Float16)q8(v.z, scale);
  pk.h[3] = (_Float16)q8(v.w, scale);
  if (col < 4096) *(uint2*)(Qh + (size_t)s * 4096 + col) = pk.u;
  else            *(uint2*)(Kh + (size_t)s * 1024 + (col - 4096)) = pk.u;
}

// quantize V slice of Y with LDS-tiled transpose -> Vt[8][128][2048]
// block: 64 s x 64 d; grid (32 s-tiles, 8 kvh, 2 d-halves)
__global__ __launch_bounds__(256) void k_quant_vt(
    const float* __restrict__ Y, _Float16* __restrict__ Vt,
    const float* __restrict__ scal)
{
  __shared__ _Float16 sT[64][72];      // [d][s], stride 144 B (16B-aligned rows)
  const int s0 = blockIdx.x * 64, kvh = blockIdx.y, dh = blockIdx.z;
  const float scale = fmaxf(scal[3], 1e-8f) / QMAXF;
  const int d = threadIdx.x & 63, srow = threadIdx.x >> 6;
#pragma unroll
  for (int i = 0; i < 16; i++){
    int s = srow + i * 4;
    float v = Y[(size_t)(s0 + s) * 6144 + 5120 + kvh * 128 + dh * 64 + d];
    sT[d][s] = (_Float16)q8(v, scale);
  }
  __syncthreads();
  const int dr = threadIdx.x >> 2, j = threadIdx.x & 3;   // 64 d-rows x 4 lanes
  _Float16* dst = Vt + (size_t)kvh * HEADD * S_LEN + (size_t)(dh * 64 + dr) * S_LEN + s0 + j * 16;
  *(uint4*)(dst)     = *(const uint4*)(&sT[dr][j * 16]);
  *(uint4*)(dst + 8) = *(const uint4*)(&sT[dr][j * 16 + 8]);
}

// ---------------- GEMM: C[M][N] = (A[M][K] . B[N][K]^T) * sa * sb[n] ----------------
// R8: 128x128 tile, BK=64, double-buffered counted-vmcnt pipeline (T3/T4),
// 16B-chunk XOR-swizzled LDS (conflict-free ds_read_b128), XCD-swizzled grid.
// LDS 64KB -> 2 blocks/CU. grid.x MUST be 16 (hardcoded in swizzle).
__global__ __launch_bounds__(256, 2) void k_gemm_nt(
    const _Float16* __restrict__ A, const _Float16* __restrict__ B,
    const float* __restrict__ amax_a, const float* __restrict__ sb,
    float* __restrict__ C, int M, int N, int K)
{
  __shared__ _Float16 sA[2][8192];   // [buf][128 rows][64 k] swizzled, 32 KB
  __shared__ _Float16 sB[2][8192];

  // T1 XCD swizzle (nwg = 16*gridDim.y, both GEMMs have nwg%8==0)
  const int nwg  = 16 * gridDim.y;
  const int orig = blockIdx.x + 16 * blockIdx.y;
  const int wg   = (orig & 7) * (nwg >> 3) + (orig >> 3);
  const int m0 = (wg & 15) * 128;
  const int n0 = (wg >> 4) * 128;

  const int tid = threadIdx.x;
  const int w = tid >> 6, lane = tid & 63;
  const int quad = lane >> 4, l16 = lane & 15;
  const int wm = (w & 1) * 64, wn = (w >> 1) * 64;
  floatx4 acc[4][4] = {};

  // staging: inst i covers rows [i*32, i*32+32); thread t -> row i*32 + (t>>3),
  // chunk pos p = t&7 holds source chunk p ^ (row&7) (pre-swizzled source).
  const int strow = tid >> 3;                       // 0..31
  const int stchk = (tid & 7) ^ (strow & 7);
  const _Float16* gA = A + (size_t)(m0 + strow) * K + stchk * 8;
  const _Float16* gB = B + (size_t)(n0 + strow) * K + stchk * 8;

  // read offsets: row r (r&7 == l16&7), source chunk c = kk*4+quad at
  // swizzled pos c ^ (l16&7); offsets in halves (row stride 64).
  int offA[4][2], offB[4][2];
#pragma unroll
  for (int i = 0; i < 4; i++)
#pragma unroll
    for (int kk = 0; kk < 2; kk++){
      int c = kk * 4 + quad;
      offA[i][kk] = (wm + i * 16 + l16) * 64 + (c ^ (l16 & 7)) * 8;
      offB[i][kk] = (wn + i * 16 + l16) * 64 + (c ^ (l16 & 7)) * 8;
    }

  auto stage = [&](int kt, int buf){
    const _Float16* a = gA + (size_t)kt * 64;
    const _Float16* b = gB + (size_t)kt * 64;
    _Float16* dA = sA[buf] + w * 512;
    _Float16* dB = sB[buf] + w * 512;
#pragma unroll
    for (int i = 0; i < 4; i++){
      gload_lds16(a + (size_t)i * 32 * K, dA + i * 2048);
      gload_lds16(b + (size_t)i * 32 * K, dB + i * 2048);
    }
  };

  const int NT = K >> 6;            // K=4096 -> 64 tiles
  stage(0, 0);                      // 8 loads (L0)
  stage(1, 1);                      // 8 loads (L1)
  asm volatile("s_waitcnt vmcnt(8)" ::: "memory");   // L0 landed, L1 flies
  __builtin_amdgcn_s_barrier();

  for (int t = 0; t < NT; ++t){
    const _Float16* a = sA[t & 1];
    const _Float16* b = sB[t & 1];
    half8 af[4][2], bf[4][2];
#pragma unroll
    for (int i = 0; i < 4; i++)
#pragma unroll
      for (int kk = 0; kk < 2; kk++){
        af[i][kk] = *(const half8*)(a + offA[i][kk]);
        bf[i][kk] = *(const half8*)(b + offB[i][kk]);
      }
#pragma unroll
    for (int kk = 0; kk < 2; kk++)
#pragma unroll
      for (int i = 0; i < 4; i++)
#pragma unroll
        for (int j = 0; j < 4; j++)
          acc[i][j] = __builtin_amdgcn_mfma_f32_16x16x32_f16(af[i][kk], bf[j][kk], acc[i][j], 0, 0, 0);
    // (A) all waves done reading buf[t&1] (read data consumed by MFMAs above)
    asm volatile("" ::: "memory");
    __builtin_amdgcn_s_barrier();
    if (t + 2 < NT){
      stage(t + 2, t & 1);                               // overwrite freed buf
      asm volatile("s_waitcnt vmcnt(8)" ::: "memory");   // t+1 landed, t+2 flies
    } else {
      asm volatile("s_waitcnt vmcnt(0)" ::: "memory");   // tail drain
    }
    // (B) all waves agree tile t+1 is resident
    __builtin_amdgcn_s_barrier();
    asm volatile("" ::: "memory");
  }

  const float sa = fmaxf(*amax_a, 1e-8f) / QMAXF;
#pragma unroll
  for (int i = 0; i < 4; i++){
    int row = m0 + wm + i * 16 + quad * 4;
#pragma unroll
    for (int j = 0; j < 4; j++){
      int col = n0 + wn + j * 16 + l16;
      float sc2 = sa * sb[col];
#pragma unroll
      for (int rr = 0; rr < 4; rr++)
        C[(size_t)(row + rr) * N + col] = acc[i][j][rr] * sc2;
    }
  }
}

// ---------------- flash attention, swapped-operand, exact quantized softmax ----------------
// grid (16,32) XCD-swizzled: each XCD owns one kvh (64 blocks = 4 h x 16 pairs)
// -> K/V panels (1 MB) L2-resident per XCD. qb in {pair, 31-pair}, 33 tiles.
// Swapped QK: c = mfma(kf, qf) -> lane l16 = q-row, reg (nt,quad,rr) = k.
// P stays in registers; PV B-frag built via cvt_pkrtz + shfl; PV swapped.
// LDS 64KB: K,V both double-buffered, 1 barrier/tile both passes, DMA 1 ahead.
__global__ __launch_bounds__(256, 2) void k_attn(
    const _Float16* __restrict__ Qh,  // [2048][4096]  (s, h*128+d) int-f16
    const _Float16* __restrict__ Kh,  // [2048][1024]  (s, kvh*128+d)
    const _Float16* __restrict__ Vt,  // [8][128][2048] (kvh, d, s)
    const float* __restrict__ scal,
    float* __restrict__ AO)           // [2048][4096] fp32
{
  const int orig = blockIdx.x + 16 * blockIdx.y;     // 0..511
  const int wg   = (orig & 7) * 64 + (orig >> 3);    // XCD x -> kvh x
  const int pair = wg & 15;
  const int h    = wg >> 4;      // 0..31
  const int kvh  = h >> 2;       // GQA groups=4
  const int tid  = threadIdx.x;
  const int wid  = tid >> 6, lane = tid & 63;
  const int quad = lane >> 4, l16 = lane & 15;

  __shared__ _Float16 sK[2][8192];    // K tile [64 k][128 d], dbuf
  __shared__ _Float16 sV[2][8192];    // V tile [128 d][64 k], dbuf

  const float s_q = fmaxf(scal[1], 1e-8f) / QMAXF;
  const float s_k = fmaxf(scal[2], 1e-8f) / QMAXF;
  const float s_v = fmaxf(scal[3], 1e-8f) / QMAXF;
  const float qkscale = s_q * s_k * 0.08838834764831845f;  // * HD^-0.5
  const float osc = s_v * (1.0f / QMAXF);

  // ---- staging addresses (pre-swizzled global source, linear LDS dest) ----
  const int srow7 = (wid * 4 + quad) & 7;
  const int sch   = (l16 & 8) | ((l16 ^ srow7) & 7);
  const _Float16* gKs = Kh + (size_t)(wid * 4 + quad) * 1024 + (size_t)kvh * 128 + sch * 8;
  const int vrg = lane >> 3, vp = lane & 7;
  const _Float16* gVs = Vt + (size_t)kvh * (HEADD * S_LEN)
                           + (size_t)(wid * 8 + vrg) * S_LEN + ((vp ^ vrg) & 7) * 8;

  // ---- swizzled read offsets ----
  int krd[4];                                   // K read: row = nt*16+l16 (row&7 == l16&7)
#pragma unroll
  for (int kk = 0; kk < 4; kk++){
    int c = kk * 4 + quad;
    krd[kk] = l16 * 128 + ((c & 8) | ((c ^ (l16 & 7)) & 7)) * 8;
  }
  const int vrd0 = l16 * 64 + ((quad       ^ (l16 & 7)) & 7) * 8;  // V read, k 0..31
  const int vrd1 = l16 * 64 + (((quad ^ 4) ^ (l16 & 7)) & 7) * 8;  // V read, k 32..63

  // P-exchange source lanes: target word w needs lane quad' = 2*(quad&1) + (w>>1)
  const int sl0 = l16 + 32 * (quad & 1);    // w = 0,1
  const int sl1 = sl0 + 16;                 // w = 2,3

  auto stage_k = [&](int kt, int buf){
    const _Float16* g = gKs + (size_t)kt * 65536;
    _Float16* d = sK[buf] + wid * 512;
    gload_lds16(g,          d);
    gload_lds16(g + 16384,  d + 2048);
    gload_lds16(g + 32768,  d + 4096);
    gload_lds16(g + 49152,  d + 6144);
  };
  auto stage_v = [&](int kt, int buf){
    const _Float16* g = gVs + (size_t)kt * 64;
    _Float16* d = sV[buf] + wid * 512;
    gload_lds16(g,          d);
    gload_lds16(g + 65536,  d + 2048);
    gload_lds16(g + 131072, d + 4096);
    gload_lds16(g + 196608, d + 6144);
  };

  for (int half = 0; half < 2; half++){
    const int qb = half ? (31 - pair) : pair;
    const int ql = qb * 64 + wid * 16 + l16;     // this lane's q-row (swapped layout)
    half8 qf[4];
#pragma unroll
    for (int kk = 0; kk < 4; kk++)
      qf[kk] = *(const half8*)(Qh + (size_t)ql * 4096 + h * 128 + kk * 32 + quad * 8);

    float m = -__builtin_inff(), l = 0.f;

    // ---- pass 1: exact row max + denominator ----
    stage_k(0, 0);
    __syncthreads();
    for (int kt = 0; kt <= qb; ++kt){
      if (kt < qb) stage_k(kt + 1, (kt + 1) & 1);
      const _Float16* kb = sK[kt & 1];
      const bool diag = (kt == qb);
      float s[4][4];
      __builtin_amdgcn_s_setprio(1);
#pragma unroll
      for (int nt = 0; nt < 4; nt++){
        floatx4 c = {};
#pragma unroll
        for (int kk = 0; kk < 4; kk++){
          half8 kf = *(const half8*)(kb + nt * 2048 + krd[kk]);
          c = __builtin_amdgcn_mfma_f32_16x16x32_f16(kf, qf[kk], c, 0, 0, 0);
        }
#pragma unroll
        for (int rr = 0; rr < 4; rr++){
          int kpos = kt * 64 + nt * 16 + quad * 4 + rr;
          float v = c[rr] * qkscale;
          s[nt][rr] = (diag && kpos > ql) ? -__builtin_inff() : v;
        }
      }
      __builtin_amdgcn_s_setprio(0);
      float tm = s[0][0];
#pragma unroll
      for (int nt = 0; nt < 4; nt++)
#pragma unroll
        for (int rr = 0; rr < 4; rr++) tm = fmaxf(tm, s[nt][rr]);
      tm = quad_max(tm);
      float mnew = fmaxf(m, tm);
      float ls = 0.f;
#pragma unroll
      for (int nt = 0; nt < 4; nt++)
#pragma unroll
        for (int rr = 0; rr < 4; rr++) ls += __expf(s[nt][rr] - mnew);
      ls = quad_sum(ls);
      l = l * __expf(m - mnew) + ls;
      m = mnew;
      __syncthreads();                           // drains vmcnt -> next tile ready
    }
    const float il = QMAXF * __builtin_amdgcn_rcpf(l);

    // ---- pass 2: recompute, quantize probs in-register, PV ----
    floatx4 accO[8] = {};
    stage_k(0, 0); stage_v(0, 0);
    __syncthreads();
    for (int kt = 0; kt <= qb; ++kt){
      if (kt < qb){ stage_k(kt + 1, (kt + 1) & 1); stage_v(kt + 1, (kt + 1) & 1); }
      const _Float16* kb = sK[kt & 1];
      const _Float16* vb = sV[kt & 1];
      const bool diag = (kt == qb);
      float p[4][4];
      __builtin_amdgcn_s_setprio(1);
#pragma unroll
      for (int nt = 0; nt < 4; nt++){
        floatx4 c = {};
#pragma unroll
        for (int kk = 0; kk < 4; kk++){
          half8 kf = *(const half8*)(kb + nt * 2048 + krd[kk]);
          c = __builtin_amdgcn_mfma_f32_16x16x32_f16(kf, qf[kk], c, 0, 0, 0);
        }
#pragma unroll
        for (int rr = 0; rr < 4; rr++) p[nt][rr] = c[rr];
      }
      __builtin_amdgcn_s_setprio(0);
      // quantize: pq = min(rint(exp(s - m) * 127/l), 127), 0 beyond diagonal
      unsigned ph[4][2];
#pragma unroll
      for (int nt = 0; nt < 4; nt++){
        float pq[4];
#pragma unroll
        for (int rr = 0; rr < 4; rr++){
          int kpos = kt * 64 + nt * 16 + quad * 4 + rr;
          float v = fminf(rintf(__expf(p[nt][rr] * qkscale - m) * il), 127.f);
          pq[rr] = (diag && kpos > ql) ? 0.f : v;
        }
        ph[nt][0] = __builtin_bit_cast(unsigned, __builtin_amdgcn_cvt_pkrtz(pq[0], pq[1]));
        ph[nt][1] = __builtin_bit_cast(unsigned, __builtin_amdgcn_cvt_pkrtz(pq[2], pq[3]));
      }
      // exchange: build PV B-frags pb[ks]: word w <- lane quad'=2*(quad&1)+(w>>1),
      // reg ph[2ks + (quad>>1)][w&1]
      half8 pb[2];
      const bool hi = (quad >= 2);
#pragma unroll
      for (int ks = 0; ks < 2; ks++){
        unsigned wa0 = __shfl((int)ph[2 * ks][0],     sl0);
        unsigned wb0 = __shfl((int)ph[2 * ks + 1][0], sl0);
        unsigned wa1 = __shfl((int)ph[2 * ks][1],     sl0);
        unsigned wb1 = __shfl((int)ph[2 * ks + 1][1], sl0);
        unsigned wa2 = __shfl((int)ph[2 * ks][0],     sl1);
        unsigned wb2 = __shfl((int)ph[2 * ks + 1][0], sl1);
        unsigned wa3 = __shfl((int)ph[2 * ks][1],     sl1);
        unsigned wb3 = __shfl((int)ph[2 * ks + 1][1], sl1);
        union { unsigned w[4]; half8 v; } u;
        u.w[0] = hi ? wb0 : wa0;
        u.w[1] = hi ? wb1 : wa1;
        u.w[2] = hi ? wb2 : wa2;
        u.w[3] = hi ? wb3 : wa3;
        pb[ks] = u.v;
      }
      __builtin_amdgcn_s_setprio(1);
#pragma unroll
      for (int dt = 0; dt < 8; dt++){
        half8 v0 = *(const half8*)(vb + dt * 1024 + vrd0);
        half8 v1 = *(const half8*)(vb + dt * 1024 + vrd1);
        accO[dt] = __builtin_amdgcn_mfma_f32_16x16x32_f16(v0, pb[0], accO[dt], 0, 0, 0);
        accO[dt] = __builtin_amdgcn_mfma_f32_16x16x32_f16(v1, pb[1], accO[dt], 0, 0, 0);
      }
      __builtin_amdgcn_s_setprio(0);
      __syncthreads();                           // drains vmcnt -> next tile ready
    }

    // epilogue: lane l16 = q-row, reg (dt,quad,rr) = d -> coalesced float4
#pragma unroll
    for (int dt = 0; dt < 8; dt++){
      float4 o;
      o.x = accO[dt][0] * osc; o.y = accO[dt][1] * osc;
      o.z = accO[dt][2] * osc; o.w = accO[dt][3] * osc;
      *(float4*)(AO + (size_t)ql * 4096 + h * 128 + dt * 16 + quad * 4) = o;
    }
  }
}

// ---------------- launch ----------------
extern "C" void kernel_launch(void* const* d_in, const int* in_sizes, int n_in,
                              void* d_out, int out_size, void* d_ws, size_t ws_size,
                              hipStream_t stream)
{
  const float* hidden = (const float*)d_in[0];
  // d_in[1] attention_mask: deterministic causal -> computed analytically
  const float* cosb = (const float*)d_in[2];
  const float* sinb = (const float*)d_in[3];
  const float* wq = (const float*)d_in[4];
  const float* wk = (const float*)d_in[5];
  const float* wv = (const float*)d_in[6];
  const float* wo = (const float*)d_in[7];
  float* out = (float*)d_out;

  char* ws = (char*)d_ws;
  size_t off = 0;
  auto alloc = [&](size_t bytes){ size_t o = off; off += (bytes + 255) & ~(size_t)255; return o; };
  float*    scal  = (float*)   (ws + alloc(64));                       // amax: x,q,k,v,ao
  float*    wsc   = (float*)   (ws + alloc(10240 * 4));                // per-row weight scales
  float*    qpart = (float*)   (ws + alloc(ROPE_BLOCKS * 4));
  float*    kpart = (float*)   (ws + alloc(ROPE_BLOCKS * 4));
  _Float16* Wall  = (_Float16*)(ws + alloc((size_t)6144 * 4096 * 2));  // wq|wk|wv int-f16
  _Float16* Wo    = (_Float16*)(ws + alloc((size_t)4096 * 4096 * 2));
  _Float16* Xq    = (_Float16*)(ws + alloc((size_t)2048 * 4096 * 2));
  float*    Y     = (float*)   (ws + alloc((size_t)2048 * 6144 * 4));  // qkv proj fp32
  // aliases (lifetimes disjoint): total ws ~151 MB
  _Float16* Qh  = Xq;                                   // written after GEMM1 read of Xq
  _Float16* Kh  = Wall;                                 // written after GEMM1 read of Wall
  _Float16* Vt  = Wall + (size_t)2048 * 1024;
  float*    AO  = Y;                                    // written after Y consumed
  _Float16* AOq = (_Float16*)((char*)Y + (size_t)2048 * 4096 * 4);

  unsigned* su = (unsigned*)scal;

  k_init<<<dim3(1), dim3(64), 0, stream>>>(scal);
  k_quant_w<<<dim3(10240), dim3(256), 0, stream>>>(wq, wk, wv, wo, Wall, Wo, wsc);
  k_amax<<<dim3(256), dim3(256), 0, stream>>>(hidden, (size_t)(2048 * 4096 / 4), su + 0);
  k_quant<<<dim3(2048), dim3(256), 0, stream>>>(hidden, Xq, (size_t)(2048 * 4096 / 4), scal + 0);
  k_gemm_nt<<<dim3(16, 48), dim3(256), 0, stream>>>(Xq, Wall, scal + 0, wsc, Y, 2048, 6144, 4096);
  k_rope<<<dim3(ROPE_BLOCKS), dim3(256), 0, stream>>>(Y, cosb, sinb, qpart, kpart);
  k_reduce_qk<<<dim3(2), dim3(256), 0, stream>>>(qpart, kpart, scal);
  k_amax_v<<<dim3(256), dim3(256), 0, stream>>>(Y, su + 3);
  k_quant_qk<<<dim3(10240), dim3(256), 0, stream>>>(Y, Qh, Kh, scal);
  k_quant_vt<<<dim3(32, 8, 2), dim3(256), 0, stream>>>(Y, Vt, scal);
  k_attn<<<dim3(16, 32), dim3(256), 0, stream>>>(Qh, Kh, Vt, scal, AO);
  k_amax<<<dim3(256), dim3(256), 0, stream>>>(AO, (size_t)(2048 * 4096 / 4), su + 4);
  k_quant<<<dim3(2048), dim3(256), 0, stream>>>(AO, AOq, (size_t)(2048 * 4096 / 4), scal + 4);
  k_gemm_nt<<<dim3(16, 32), dim3(256), 0, stream>>>(AOq, Wo, scal + 4, wsc + 6144, out, 2048, 4096, 4096);
}

// Round 7
// 642.414 us; speedup vs baseline: 1.1449x; 1.0027x over previous
//
#include <hip/hip_runtime.h>
#include <cstdint>
#include <cstddef>

// QuantLlamaAttention: int8 fake-quant Llama attention block, MI355X (gfx950).
// All matmuls carry quantized INTEGER values in _Float16 (exact for |v|<=2048)
// through mfma_f32_16x16x32_f16, fp32 accumulate, scales applied in epilogue.
// softmax prob amax is exactly 1.0 (causal row 0) -> static prob scale 1/127,
// enabling a two-pass flash attention with exact quantization (no S matrix).
//
// R1: block partials / 1 atomic per block (amax).
// R2: 368->147us attn: __expf, diag masking, q-pairing, gload_lds GEMM.
// R3/R4: launch_bounds(256,4) VGPR cap spills -> regression; reverted.
// R5: gload_lds pre-swizzled K/V staging; occupancy not the lever for attn.
// R6: swapped-operand attn (mfma(K,Q)): lane owns q-row, P in-register via
//     cvt_pkrtz+shfl, PV swapped, 1 barrier/tile. attn off the top-5.
// R8: GEMM BK=64 dbuf counted-vmcnt: REGRESSION 143->165us. Occ 30->15
//     (64KB LDS = 2 blocks/CU) + vmcnt(8) waits for loads only 1 iter old
//     (~300cy < latency) with no TLP to hide. BUT: chunk-XOR swizzle zeroed
//     BANK_CONFLICT (1.26e7 -> 0) and XCD swizzle cut FETCH 205->156MB.
// R9: R5 GEMM structure (16KB LDS, BK=32, 2 barriers, 3 blocks/CU, 721TF)
//     + R8's two proven wins: chunk-XOR swizzle adapted to [128][32]
//     (pos p of row r holds src chunk p^((r>>1)&3); balanced 4-bank groups)
//     and the XCD grid swizzle. No pipeline games.

#define S_LEN   2048
#define HDIM    4096
#define NHEADS  32
#define NKVH    8
#define HEADD   128
#define QMAXF   127.0f
#define ROPE_BLOCKS 20480

typedef _Float16 half8  __attribute__((ext_vector_type(8)));
typedef float    floatx4 __attribute__((ext_vector_type(4)));

// ---------------- helpers ----------------
__device__ __forceinline__ float wave_max64(float v){
#pragma unroll
  for (int off = 32; off > 0; off >>= 1) v = fmaxf(v, __shfl_xor(v, off));
  return v;
}
__device__ __forceinline__ float quad_max(float v){
  v = fmaxf(v, __shfl_xor(v, 16));
  v = fmaxf(v, __shfl_xor(v, 32));
  return v;
}
__device__ __forceinline__ float quad_sum(float v){
  v += __shfl_xor(v, 16);
  v += __shfl_xor(v, 32);
  return v;
}
__device__ __forceinline__ void atomic_max_f(unsigned* p, float v){
  atomicMax(p, __float_as_uint(v));   // v >= 0: uint bits order-preserving
}
__device__ __forceinline__ float q8(float x, float scale){
  return fminf(fmaxf(rintf(x / scale), -128.f), 127.f);  // rintf = half-even, matches jnp.round
}
// async global->LDS, 16B per lane. HW: LDS dest = wave-uniform base + lane*16.
__device__ __forceinline__ void gload_lds16(const _Float16* g, _Float16* l){
  __builtin_amdgcn_global_load_lds((const __attribute__((address_space(1))) void*)g,
                                   (__attribute__((address_space(3))) void*)l, 16, 0, 0);
}

// block-level max of per-wave maxima (256 threads = 4 waves), then ONE atomic
__device__ __forceinline__ void block_atomic_max(float m, unsigned* out){
  m = wave_max64(m);
  __shared__ float red[4];
  int wid = threadIdx.x >> 6;
  if ((threadIdx.x & 63) == 0) red[wid] = m;
  __syncthreads();
  if (threadIdx.x == 0)
    atomic_max_f(out, fmaxf(fmaxf(red[0], red[1]), fmaxf(red[2], red[3])));
}

// ---------------- tiny kernels ----------------
__global__ void k_init(float* scal){ if (threadIdx.x < 16) scal[threadIdx.x] = 0.0f; }

__global__ void k_amax(const float* __restrict__ x, size_t n4, unsigned* __restrict__ out){
  size_t i = (size_t)blockIdx.x * blockDim.x + threadIdx.x;
  size_t stride = (size_t)gridDim.x * blockDim.x;
  float m = 0.f;
  for (; i < n4; i += stride){
    float4 v = ((const float4*)x)[i];
    m = fmaxf(m, fmaxf(fmaxf(fabsf(v.x), fabsf(v.y)), fmaxf(fabsf(v.z), fabsf(v.w))));
  }
  block_atomic_max(m, out);
}

// amax over the V slice (cols [5120,6144)) of Y[2048][6144]
__global__ void k_amax_v(const float* __restrict__ Y, unsigned* __restrict__ out){
  size_t i = (size_t)blockIdx.x * blockDim.x + threadIdx.x;
  size_t stride = (size_t)gridDim.x * blockDim.x;
  float m = 0.f;
  for (size_t e = i; e < (size_t)S_LEN * 1024; e += stride){
    size_t s = e >> 10; int c = (int)(e & 1023);
    m = fmaxf(m, fabsf(Y[s * 6144 + 5120 + c]));
  }
  block_atomic_max(m, out);
}

// per-tensor quantize fp32 -> integer-valued f16
__global__ void k_quant(const float* __restrict__ x, _Float16* __restrict__ q,
                        size_t n4, const float* __restrict__ amax){
  float scale = fmaxf(*amax, 1e-8f) / QMAXF;
  size_t i = (size_t)blockIdx.x * blockDim.x + threadIdx.x;
  size_t stride = (size_t)gridDim.x * blockDim.x;
  for (; i < n4; i += stride){
    float4 v = ((const float4*)x)[i];
    union { _Float16 h[4]; uint2 u; } pk;
    pk.h[0] = (_Float16)q8(v.x, scale);
    pk.h[1] = (_Float16)q8(v.y, scale);
    pk.h[2] = (_Float16)q8(v.z, scale);
    pk.h[3] = (_Float16)q8(v.w, scale);
    ((uint2*)q)[i] = pk.u;
  }
}

// per-row weight quantization: rows 0..6143 -> Wall (wq|wk|wv), 6144..10239 -> Wo
__global__ __launch_bounds__(256) void k_quant_w(
    const float* __restrict__ wq, const float* __restrict__ wk,
    const float* __restrict__ wv, const float* __restrict__ wo,
    _Float16* __restrict__ Wall, _Float16* __restrict__ Wo,
    float* __restrict__ wsc)
{
  int row = blockIdx.x;
  const float* src; _Float16* dst;
  if (row < 4096)      { src = wq + (size_t)row * HDIM;          dst = Wall + (size_t)row * HDIM; }
  else if (row < 5120) { src = wk + (size_t)(row - 4096) * HDIM; dst = Wall + (size_t)row * HDIM; }
  else if (row < 6144) { src = wv + (size_t)(row - 5120) * HDIM; dst = Wall + (size_t)row * HDIM; }
  else                 { src = wo + (size_t)(row - 6144) * HDIM; dst = Wo + (size_t)(row - 6144) * HDIM; }
  float4 v[4]; float m = 0.f;
#pragma unroll
  for (int i = 0; i < 4; i++){
    v[i] = ((const float4*)src)[threadIdx.x + i * 256];
    m = fmaxf(m, fmaxf(fmaxf(fabsf(v[i].x), fabsf(v[i].y)), fmaxf(fabsf(v[i].z), fabsf(v[i].w))));
  }
  m = wave_max64(m);
  __shared__ float red[4];
  int wid = threadIdx.x >> 6;
  if ((threadIdx.x & 63) == 0) red[wid] = m;
  __syncthreads();
  float am = fmaxf(fmaxf(red[0], red[1]), fmaxf(red[2], red[3]));
  float scale = fmaxf(am, 1e-8f) / QMAXF;
  if (threadIdx.x == 0) wsc[row] = scale;
#pragma unroll
  for (int i = 0; i < 4; i++){
    union { _Float16 h[4]; uint2 u; } pk;
    pk.h[0] = (_Float16)q8(v[i].x, scale);
    pk.h[1] = (_Float16)q8(v[i].y, scale);
    pk.h[2] = (_Float16)q8(v[i].z, scale);
    pk.h[3] = (_Float16)q8(v[i].w, scale);
    ((uint2*)dst)[threadIdx.x + i * 256] = pk.u;
  }
}

// RoPE in-place on Y (q: heads 0..31, k: heads 32..39) + per-block partials
__global__ __launch_bounds__(256) void k_rope(
    float* __restrict__ Y, const float* __restrict__ cosb,
    const float* __restrict__ sinb,
    float* __restrict__ qpart, float* __restrict__ kpart)
{
  int idx = blockIdx.x * 256 + threadIdx.x;   // 2048*40*64 total
  int s = idx / (40 * 64);
  int rem = idx - s * 40 * 64;
  int head = rem >> 6;        // wave-uniform (64 threads per head slot)
  int d = rem & 63;
  size_t base = (size_t)s * 6144 + (head < 32 ? head * 128 : 4096 + (head - 32) * 128);
  float x1 = Y[base + d], x2 = Y[base + d + 64];
  float c1 = cosb[s * 128 + d],      s1 = sinb[s * 128 + d];
  float c2 = cosb[s * 128 + d + 64], s2 = sinb[s * 128 + d + 64];
  float o1 = x1 * c1 - x2 * s1;
  float o2 = x2 * c2 + x1 * s2;
  Y[base + d] = o1; Y[base + d + 64] = o2;
  float m = wave_max64(fmaxf(fabsf(o1), fabsf(o2)));
  __shared__ float wmax[4]; __shared__ int wisq[4];
  int wid = threadIdx.x >> 6;
  if ((threadIdx.x & 63) == 0){ wmax[wid] = m; wisq[wid] = (head < 32); }
  __syncthreads();
  if (threadIdx.x == 0){
    float qm = 0.f, km = 0.f;
#pragma unroll
    for (int w = 0; w < 4; w++){
      if (wisq[w]) qm = fmaxf(qm, wmax[w]); else km = fmaxf(km, wmax[w]);
    }
    qpart[blockIdx.x] = qm; kpart[blockIdx.x] = km;
  }
}

// reduce rope partials: block 0 -> scal[1] (q), block 1 -> scal[2] (k)
__global__ __launch_bounds__(256) void k_reduce_qk(
    const float* __restrict__ qpart, const float* __restrict__ kpart,
    float* __restrict__ scal)
{
  const float* src = blockIdx.x ? kpart : qpart;
  float m = 0.f;
  for (int i = threadIdx.x; i < ROPE_BLOCKS; i += 256) m = fmaxf(m, src[i]);
  m = wave_max64(m);
  __shared__ float red[4];
  int wid = threadIdx.x >> 6;
  if ((threadIdx.x & 63) == 0) red[wid] = m;
  __syncthreads();
  if (threadIdx.x == 0)
    scal[1 + blockIdx.x] = fmaxf(fmaxf(red[0], red[1]), fmaxf(red[2], red[3]));
}

// quantize Q,K slices of Y (cols [0,5120)) -> Qh[2048][4096], Kh[2048][1024]
__global__ __launch_bounds__(256) void k_quant_qk(
    const float* __restrict__ Y, _Float16* __restrict__ Qh,
    _Float16* __restrict__ Kh, const float* __restrict__ scal)
{
  int i = blockIdx.x * 256 + threadIdx.x;       // 2048*5120/4 float4 units
  int s = i / 1280, c4 = i - s * 1280;
  int col = c4 * 4;
  float4 v = *(const float4*)(Y + (size_t)s * 6144 + col);
  float scale = fmaxf(col < 4096 ? scal[1] : scal[2], 1e-8f) / QMAXF;
  union { _Float16 h[4]; uint2 u; } pk;
  pk.h[0] = (_Float16)q8(v.x, scale);
  pk.h[1] = (_Float16)q8(v.y, scale);
  pk.h[2] = (_Float16)q8(v.z, scale);
  pk.h[3] = (_Float16)q8(v.w, scale);
  if (col < 4096) *(uint2*)(Qh + (size_t)s * 4096 + col) = pk.u;
  else            *(uint2*)(Kh + (size_t)s * 1024 + (col - 4096)) = pk.u;
}

// quantize V slice of Y with LDS-tiled transpose -> Vt[8][128][2048]
// block: 64 s x 64 d; grid (32 s-tiles, 8 kvh, 2 d-halves)
__global__ __launch_bounds__(256) void k_quant_vt(
    const float* __restrict__ Y, _Float16* __restrict__ Vt,
    const float* __restrict__ scal)
{
  __shared__ _Float16 sT[64][72];      // [d][s], stride 144 B (16B-aligned rows)
  const int s0 = blockIdx.x * 64, kvh = blockIdx.y, dh = blockIdx.z;
  const float scale = fmaxf(scal[3], 1e-8f) / QMAXF;
  const int d = threadIdx.x & 63, srow = threadIdx.x >> 6;
#pragma unroll
  for (int i = 0; i < 16; i++){
    int s = srow + i * 4;
    float v = Y[(size_t)(s0 + s) * 6144 + 5120 + kvh * 128 + dh * 64 + d];
    sT[d][s] = (_Float16)q8(v, scale);
  }
  __syncthreads();
  const int dr = threadIdx.x >> 2, j = threadIdx.x & 3;   // 64 d-rows x 4 lanes
  _Float16* dst = Vt + (size_t)kvh * HEADD * S_LEN + (size_t)(dh * 64 + dr) * S_LEN + s0 + j * 16;
  *(uint4*)(dst)     = *(const uint4*)(&sT[dr][j * 16]);
  *(uint4*)(dst + 8) = *(const uint4*)(&sT[dr][j * 16 + 8]);
}

// ---------------- GEMM: C[M][N] = (A[M][K] . B[N][K]^T) * sa * sb[n] ----------------
// R9: m97 structure (16KB LDS, BK=32, 2 barriers/iter, grid-capped 3 blocks/CU)
// + chunk-XOR swizzled LDS: pos p of row r holds source chunk p^((r>>1)&3)
//   (pre-swizzled gload source, involution on read) -> balanced 4-bank groups,
//   zero conflicts (proven R8)
// + T1 XCD swizzle (proven R8: FETCH -25%). grid.x MUST be 16.
__global__ __launch_bounds__(256) void k_gemm_nt(
    const _Float16* __restrict__ A, const _Float16* __restrict__ B,
    const float* __restrict__ amax_a, const float* __restrict__ sb,
    float* __restrict__ C, int M, int N, int K)
{
  __shared__ _Float16 sA[128 * 32];
  __shared__ _Float16 sB[128 * 32];

  // T1 XCD swizzle (nwg = 16*gridDim.y, both GEMMs have nwg%8==0)
  const int nwg  = 16 * gridDim.y;
  const int orig = blockIdx.x + 16 * blockIdx.y;
  const int wg   = (orig & 7) * (nwg >> 3) + (orig >> 3);
  const int m0 = (wg & 15) * 128;
  const int n0 = (wg >> 4) * 128;

  const int tid = threadIdx.x;
  const int w = tid >> 6, lane = tid & 63;
  const int quad = lane >> 4, l16 = lane & 15;
  const int wm = (w & 1) * 64, wn = (w >> 1) * 64;
  floatx4 acc[4][4] = {};

  // staging: wave w covers rows w*16..+15 (inst 0) and +64 (inst 1);
  // lane l -> row w*16 + l/4, chunk pos l%4 holds SOURCE chunk (l%4)^((l>>3)&3)
  // (row>>1)&3 = (l>>3)&3 for these rows; +64 preserves it.
  const int srow = w * 16 + (lane >> 2);
  const int scol = ((lane & 3) ^ ((lane >> 3) & 3)) * 8;
  const _Float16* gA0 = A + (size_t)(m0 + srow) * K + scol;
  const _Float16* gA1 = A + (size_t)(m0 + 64 + srow) * K + scol;
  const _Float16* gB0 = B + (size_t)(n0 + srow) * K + scol;
  const _Float16* gB1 = B + (size_t)(n0 + 64 + srow) * K + scol;
  _Float16* dA0 = sA + w * 512 + lane * 8;
  _Float16* dA1 = sA + 2048 + w * 512 + lane * 8;
  _Float16* dB0 = sB + w * 512 + lane * 8;
  _Float16* dB1 = sB + 2048 + w * 512 + lane * 8;

  // read: source chunk quad of row wm+i*16+l16 sits at pos quad^((l16>>1)&3)
  const int rpos = (quad ^ ((l16 >> 1) & 3)) * 8;

  for (int k0 = 0; k0 < K; k0 += 32){
    __syncthreads();                       // prev iter's LDS reads done
    gload_lds16(gA0 + k0, dA0);
    gload_lds16(gA1 + k0, dA1);
    gload_lds16(gB0 + k0, dB0);
    gload_lds16(gB1 + k0, dB1);
    __syncthreads();                       // drains vmcnt before barrier
    half8 af[4], bf[4];
#pragma unroll
    for (int i = 0; i < 4; i++){
      af[i] = *(const half8*)(sA + (wm + i * 16 + l16) * 32 + rpos);
      bf[i] = *(const half8*)(sB + (wn + i * 16 + l16) * 32 + rpos);
    }
#pragma unroll
    for (int i = 0; i < 4; i++)
#pragma unroll
      for (int j = 0; j < 4; j++)
        acc[i][j] = __builtin_amdgcn_mfma_f32_16x16x32_f16(af[i], bf[j], acc[i][j], 0, 0, 0);
  }
  const float sa = fmaxf(*amax_a, 1e-8f) / QMAXF;
#pragma unroll
  for (int i = 0; i < 4; i++){
    int row = m0 + wm + i * 16 + quad * 4;
#pragma unroll
    for (int j = 0; j < 4; j++){
      int col = n0 + wn + j * 16 + l16;
      float sc2 = sa * sb[col];
#pragma unroll
      for (int rr = 0; rr < 4; rr++)
        C[(size_t)(row + rr) * N + col] = acc[i][j][rr] * sc2;
    }
  }
}

// ---------------- flash attention, swapped-operand, exact quantized softmax ----------------
// grid (16,32) XCD-swizzled: each XCD owns one kvh (64 blocks = 4 h x 16 pairs)
// -> K/V panels (1 MB) L2-resident per XCD. qb in {pair, 31-pair}, 33 tiles.
// Swapped QK: c = mfma(kf, qf) -> lane l16 = q-row, reg (nt,quad,rr) = k.
// P stays in registers; PV B-frag built via cvt_pkrtz + shfl; PV swapped.
// LDS 64KB: K,V both double-buffered, 1 barrier/tile both passes, DMA 1 ahead.
__global__ __launch_bounds__(256, 2) void k_attn(
    const _Float16* __restrict__ Qh,  // [2048][4096]  (s, h*128+d) int-f16
    const _Float16* __restrict__ Kh,  // [2048][1024]  (s, kvh*128+d)
    const _Float16* __restrict__ Vt,  // [8][128][2048] (kvh, d, s)
    const float* __restrict__ scal,
    float* __restrict__ AO)           // [2048][4096] fp32
{
  const int orig = blockIdx.x + 16 * blockIdx.y;     // 0..511
  const int wg   = (orig & 7) * 64 + (orig >> 3);    // XCD x -> kvh x
  const int pair = wg & 15;
  const int h    = wg >> 4;      // 0..31
  const int kvh  = h >> 2;       // GQA groups=4
  const int tid  = threadIdx.x;
  const int wid  = tid >> 6, lane = tid & 63;
  const int quad = lane >> 4, l16 = lane & 15;

  __shared__ _Float16 sK[2][8192];    // K tile [64 k][128 d], dbuf
  __shared__ _Float16 sV[2][8192];    // V tile [128 d][64 k], dbuf

  const float s_q = fmaxf(scal[1], 1e-8f) / QMAXF;
  const float s_k = fmaxf(scal[2], 1e-8f) / QMAXF;
  const float s_v = fmaxf(scal[3], 1e-8f) / QMAXF;
  const float qkscale = s_q * s_k * 0.08838834764831845f;  // * HD^-0.5
  const float osc = s_v * (1.0f / QMAXF);

  // ---- staging addresses (pre-swizzled global source, linear LDS dest) ----
  const int srow7 = (wid * 4 + quad) & 7;
  const int sch   = (l16 & 8) | ((l16 ^ srow7) & 7);
  const _Float16* gKs = Kh + (size_t)(wid * 4 + quad) * 1024 + (size_t)kvh * 128 + sch * 8;
  const int vrg = lane >> 3, vp = lane & 7;
  const _Float16* gVs = Vt + (size_t)kvh * (HEADD * S_LEN)
                           + (size_t)(wid * 8 + vrg) * S_LEN + ((vp ^ vrg) & 7) * 8;

  // ---- swizzled read offsets ----
  int krd[4];                                   // K read: row = nt*16+l16 (row&7 == l16&7)
#pragma unroll
  for (int kk = 0; kk < 4; kk++){
    int c = kk * 4 + quad;
    krd[kk] = l16 * 128 + ((c & 8) | ((c ^ (l16 & 7)) & 7)) * 8;
  }
  const int vrd0 = l16 * 64 + ((quad       ^ (l16 & 7)) & 7) * 8;  // V read, k 0..31
  const int vrd1 = l16 * 64 + (((quad ^ 4) ^ (l16 & 7)) & 7) * 8;  // V read, k 32..63

  // P-exchange source lanes: target word w needs lane quad' = 2*(quad&1) + (w>>1)
  const int sl0 = l16 + 32 * (quad & 1);    // w = 0,1
  const int sl1 = sl0 + 16;                 // w = 2,3

  auto stage_k = [&](int kt, int buf){
    const _Float16* g = gKs + (size_t)kt * 65536;
    _Float16* d = sK[buf] + wid * 512;
    gload_lds16(g,          d);
    gload_lds16(g + 16384,  d + 2048);
    gload_lds16(g + 32768,  d + 4096);
    gload_lds16(g + 49152,  d + 6144);
  };
  auto stage_v = [&](int kt, int buf){
    const _Float16* g = gVs + (size_t)kt * 64;
    _Float16* d = sV[buf] + wid * 512;
    gload_lds16(g,          d);
    gload_lds16(g + 65536,  d + 2048);
    gload_lds16(g + 131072, d + 4096);
    gload_lds16(g + 196608, d + 6144);
  };

  for (int half = 0; half < 2; half++){
    const int qb = half ? (31 - pair) : pair;
    const int ql = qb * 64 + wid * 16 + l16;     // this lane's q-row (swapped layout)
    half8 qf[4];
#pragma unroll
    for (int kk = 0; kk < 4; kk++)
      qf[kk] = *(const half8*)(Qh + (size_t)ql * 4096 + h * 128 + kk * 32 + quad * 8);

    float m = -__builtin_inff(), l = 0.f;

    // ---- pass 1: exact row max + denominator ----
    stage_k(0, 0);
    __syncthreads();
    for (int kt = 0; kt <= qb; ++kt){
      if (kt < qb) stage_k(kt + 1, (kt + 1) & 1);
      const _Float16* kb = sK[kt & 1];
      const bool diag = (kt == qb);
      float s[4][4];
      __builtin_amdgcn_s_setprio(1);
#pragma unroll
      for (int nt = 0; nt < 4; nt++){
        floatx4 c = {};
#pragma unroll
        for (int kk = 0; kk < 4; kk++){
          half8 kf = *(const half8*)(kb + nt * 2048 + krd[kk]);
          c = __builtin_amdgcn_mfma_f32_16x16x32_f16(kf, qf[kk], c, 0, 0, 0);
        }
#pragma unroll
        for (int rr = 0; rr < 4; rr++){
          int kpos = kt * 64 + nt * 16 + quad * 4 + rr;
          float v = c[rr] * qkscale;
          s[nt][rr] = (diag && kpos > ql) ? -__builtin_inff() : v;
        }
      }
      __builtin_amdgcn_s_setprio(0);
      float tm = s[0][0];
#pragma unroll
      for (int nt = 0; nt < 4; nt++)
#pragma unroll
        for (int rr = 0; rr < 4; rr++) tm = fmaxf(tm, s[nt][rr]);
      tm = quad_max(tm);
      float mnew = fmaxf(m, tm);
      float ls = 0.f;
#pragma unroll
      for (int nt = 0; nt < 4; nt++)
#pragma unroll
        for (int rr = 0; rr < 4; rr++) ls += __expf(s[nt][rr] - mnew);
      ls = quad_sum(ls);
      l = l * __expf(m - mnew) + ls;
      m = mnew;
      __syncthreads();                           // drains vmcnt -> next tile ready
    }
    const float il = QMAXF * __builtin_amdgcn_rcpf(l);

    // ---- pass 2: recompute, quantize probs in-register, PV ----
    floatx4 accO[8] = {};
    stage_k(0, 0); stage_v(0, 0);
    __syncthreads();
    for (int kt = 0; kt <= qb; ++kt){
      if (kt < qb){ stage_k(kt + 1, (kt + 1) & 1); stage_v(kt + 1, (kt + 1) & 1); }
      const _Float16* kb = sK[kt & 1];
      const _Float16* vb = sV[kt & 1];
      const bool diag = (kt == qb);
      float p[4][4];
      __builtin_amdgcn_s_setprio(1);
#pragma unroll
      for (int nt = 0; nt < 4; nt++){
        floatx4 c = {};
#pragma unroll
        for (int kk = 0; kk < 4; kk++){
          half8 kf = *(const half8*)(kb + nt * 2048 + krd[kk]);
          c = __builtin_amdgcn_mfma_f32_16x16x32_f16(kf, qf[kk], c, 0, 0, 0);
        }
#pragma unroll
        for (int rr = 0; rr < 4; rr++) p[nt][rr] = c[rr];
      }
      __builtin_amdgcn_s_setprio(0);
      // quantize: pq = min(rint(exp(s - m) * 127/l), 127), 0 beyond diagonal
      unsigned ph[4][2];
#pragma unroll
      for (int nt = 0; nt < 4; nt++){
        float pq[4];
#pragma unroll
        for (int rr = 0; rr < 4; rr++){
          int kpos = kt * 64 + nt * 16 + quad * 4 + rr;
          float v = fminf(rintf(__expf(p[nt][rr] * qkscale - m) * il), 127.f);
          pq[rr] = (diag && kpos > ql) ? 0.f : v;
        }
        ph[nt][0] = __builtin_bit_cast(unsigned, __builtin_amdgcn_cvt_pkrtz(pq[0], pq[1]));
        ph[nt][1] = __builtin_bit_cast(unsigned, __builtin_amdgcn_cvt_pkrtz(pq[2], pq[3]));
      }
      // exchange: build PV B-frags pb[ks]: word w <- lane quad'=2*(quad&1)+(w>>1),
      // reg ph[2ks + (quad>>1)][w&1]
      half8 pb[2];
      const bool hi = (quad >= 2);
#pragma unroll
      for (int ks = 0; ks < 2; ks++){
        unsigned wa0 = __shfl((int)ph[2 * ks][0],     sl0);
        unsigned wb0 = __shfl((int)ph[2 * ks + 1][0], sl0);
        unsigned wa1 = __shfl((int)ph[2 * ks][1],     sl0);
        unsigned wb1 = __shfl((int)ph[2 * ks + 1][1], sl0);
        unsigned wa2 = __shfl((int)ph[2 * ks][0],     sl1);
        unsigned wb2 = __shfl((int)ph[2 * ks + 1][0], sl1);
        unsigned wa3 = __shfl((int)ph[2 * ks][1],     sl1);
        unsigned wb3 = __shfl((int)ph[2 * ks + 1][1], sl1);
        union { unsigned w[4]; half8 v; } u;
        u.w[0] = hi ? wb0 : wa0;
        u.w[1] = hi ? wb1 : wa1;
        u.w[2] = hi ? wb2 : wa2;
        u.w[3] = hi ? wb3 : wa3;
        pb[ks] = u.v;
      }
      __builtin_amdgcn_s_setprio(1);
#pragma unroll
      for (int dt = 0; dt < 8; dt++){
        half8 v0 = *(const half8*)(vb + dt * 1024 + vrd0);
        half8 v1 = *(const half8*)(vb + dt * 1024 + vrd1);
        accO[dt] = __builtin_amdgcn_mfma_f32_16x16x32_f16(v0, pb[0], accO[dt], 0, 0, 0);
        accO[dt] = __builtin_amdgcn_mfma_f32_16x16x32_f16(v1, pb[1], accO[dt], 0, 0, 0);
      }
      __builtin_amdgcn_s_setprio(0);
      __syncthreads();                           // drains vmcnt -> next tile ready
    }

    // epilogue: lane l16 = q-row, reg (dt,quad,rr) = d -> coalesced float4
#pragma unroll
    for (int dt = 0; dt < 8; dt++){
      float4 o;
      o.x = accO[dt][0] * osc; o.y = accO[dt][1] * osc;
      o.z = accO[dt][2] * osc; o.w = accO[dt][3] * osc;
      *(float4*)(AO + (size_t)ql * 4096 + h * 128 + dt * 16 + quad * 4) = o;
    }
  }
}

// ---------------- launch ----------------
extern "C" void kernel_launch(void* const* d_in, const int* in_sizes, int n_in,
                              void* d_out, int out_size, void* d_ws, size_t ws_size,
                              hipStream_t stream)
{
  const float* hidden = (const float*)d_in[0];
  // d_in[1] attention_mask: deterministic causal -> computed analytically
  const float* cosb = (const float*)d_in[2];
  const float* sinb = (const float*)d_in[3];
  const float* wq = (const float*)d_in[4];
  const float* wk = (const float*)d_in[5];
  const float* wv = (const float*)d_in[6];
  const float* wo = (const float*)d_in[7];
  float* out = (float*)d_out;

  char* ws = (char*)d_ws;
  size_t off = 0;
  auto alloc = [&](size_t bytes){ size_t o = off; off += (bytes + 255) & ~(size_t)255; return o; };
  float*    scal  = (float*)   (ws + alloc(64));                       // amax: x,q,k,v,ao
  float*    wsc   = (float*)   (ws + alloc(10240 * 4));                // per-row weight scales
  float*    qpart = (float*)   (ws + alloc(ROPE_BLOCKS * 4));
  float*    kpart = (float*)   (ws + alloc(ROPE_BLOCKS * 4));
  _Float16* Wall  = (_Float16*)(ws + alloc((size_t)6144 * 4096 * 2));  // wq|wk|wv int-f16
  _Float16* Wo    = (_Float16*)(ws + alloc((size_t)4096 * 4096 * 2));
  _Float16* Xq    = (_Float16*)(ws + alloc((size_t)2048 * 4096 * 2));
  float*    Y     = (float*)   (ws + alloc((size_t)2048 * 6144 * 4));  // qkv proj fp32
  // aliases (lifetimes disjoint): total ws ~151 MB
  _Float16* Qh  = Xq;                                   // written after GEMM1 read of Xq
  _Float16* Kh  = Wall;                                 // written after GEMM1 read of Wall
  _Float16* Vt  = Wall + (size_t)2048 * 1024;
  float*    AO  = Y;                                    // written after Y consumed
  _Float16* AOq = (_Float16*)((char*)Y + (size_t)2048 * 4096 * 4);

  unsigned* su = (unsigned*)scal;

  k_init<<<dim3(1), dim3(64), 0, stream>>>(scal);
  k_quant_w<<<dim3(10240), dim3(256), 0, stream>>>(wq, wk, wv, wo, Wall, Wo, wsc);
  k_amax<<<dim3(256), dim3(256), 0, stream>>>(hidden, (size_t)(2048 * 4096 / 4), su + 0);
  k_quant<<<dim3(2048), dim3(256), 0, stream>>>(hidden, Xq, (size_t)(2048 * 4096 / 4), scal + 0);
  k_gemm_nt<<<dim3(16, 48), dim3(256), 0, stream>>>(Xq, Wall, scal + 0, wsc, Y, 2048, 6144, 4096);
  k_rope<<<dim3(ROPE_BLOCKS), dim3(256), 0, stream>>>(Y, cosb, sinb, qpart, kpart);
  k_reduce_qk<<<dim3(2), dim3(256), 0, stream>>>(qpart, kpart, scal);
  k_amax_v<<<dim3(256), dim3(256), 0, stream>>>(Y, su + 3);
  k_quant_qk<<<dim3(10240), dim3(256), 0, stream>>>(Y, Qh, Kh, scal);
  k_quant_vt<<<dim3(32, 8, 2), dim3(256), 0, stream>>>(Y, Vt, scal);
  k_attn<<<dim3(16, 32), dim3(256), 0, stream>>>(Qh, Kh, Vt, scal, AO);
  k_amax<<<dim3(256), dim3(256), 0, stream>>>(AO, (size_t)(2048 * 4096 / 4), su + 4);
  k_quant<<<dim3(2048), dim3(256), 0, stream>>>(AO, AOq, (size_t)(2048 * 4096 / 4), scal + 4);
  k_gemm_nt<<<dim3(16, 32), dim3(256), 0, stream>>>(AOq, Wo, scal + 4, wsc + 6144, out, 2048, 4096, 4096);
}